// Round 1
// baseline (270.388 us; speedup 1.0000x reference)
//
#include <hip/hip_runtime.h>
#include <hip/hip_bf16.h>

#define T_DIM 1024
#define B_DIM 4
#define E_DIM 1024
#define H_DIM 16
#define HD    64
#define M_DIM (T_DIM * B_DIM)   // 4096

typedef __hip_bfloat16 bf16;
typedef __bf16 bf16x8 __attribute__((ext_vector_type(8)));
typedef __bf16 bf16x4 __attribute__((ext_vector_type(4)));
typedef float  f32x4  __attribute__((ext_vector_type(4)));

#define P4S ((size_t)M_DIM * E_DIM)   // 4194304
#define P1S ((size_t)E_DIM * E_DIM)   // 1048576

// ------------------------------------------- fused f32 -> bf16 (all 8 buffers)
// dst region is qc|kc|vc|wq|wk1|wk2|wv|wo contiguous (3*P4 + 5*P1 elems).
__global__ __launch_bounds__(256) void cvt_all(
    const float* __restrict__ q, const float* __restrict__ k,
    const float* __restrict__ v, const float* __restrict__ w0,
    const float* __restrict__ w1, const float* __restrict__ w2,
    const float* __restrict__ w3, const float* __restrict__ w4,
    __bf16* __restrict__ dst)
{
  size_t i = ((size_t)blockIdx.x * 256 + threadIdx.x) * 8;
  const float* src;
  size_t off;
  if (i < P4S)            { src = q; off = i; }
  else if (i < 2 * P4S)   { src = k; off = i - P4S; }
  else if (i < 3 * P4S)   { src = v; off = i - 2 * P4S; }
  else {
    size_t j = i - 3 * P4S;
    int wsel = (int)(j >> 20);          // /P1S
    off = j & (P1S - 1);
    const float* ws[5] = {w0, w1, w2, w3, w4};
    src = ws[wsel];
  }
  float4 a = *(const float4*)(src + off);
  float4 b = *(const float4*)(src + off + 4);
  bf16x8 o;
  o[0] = (__bf16)a.x; o[1] = (__bf16)a.y; o[2] = (__bf16)a.z; o[3] = (__bf16)a.w;
  o[4] = (__bf16)b.x; o[5] = (__bf16)b.y; o[6] = (__bf16)b.z; o[7] = (__bf16)b.w;
  *(bf16x8*)(dst + i) = o;
}

// ------------------------------------------------- async global->LDS, 16 B/lane
__device__ __forceinline__ void load_lds16(const __bf16* g, __bf16* l) {
  __builtin_amdgcn_global_load_lds(
      (__attribute__((address_space(1))) void*)(void*)g,
      (__attribute__((address_space(3))) void*)l, 16, 0, 0);
}

// --------------------------------------------------- GEMM core (128x128, BK=32)
template <typename TO>
__device__ __forceinline__ void gemm_body(
    const __bf16* __restrict__ X, const __bf16* __restrict__ W,
    const float* __restrict__ bias, TO* __restrict__ C,
    int bm, int bn, int Ndim, int Kdim, __bf16* As, __bf16* Bs)
{
  const int tid  = threadIdx.x;
  const int lane = tid & 63;
  const int wave = tid >> 6;
  const int wy = (wave >> 1) * 64;
  const int wx = (wave & 1) * 64;
  const int mrow = lane & 15, quad = lane >> 4;

  const int srow = tid >> 2;
  const int ke   = (tid & 3) * 8;
  const __bf16* gA0 = X + (size_t)(bm + srow)      * Kdim + ke;
  const __bf16* gA1 = X + (size_t)(bm + srow + 64) * Kdim + ke;
  const __bf16* gB0 = W + (size_t)(bn + srow)      * Kdim + ke;
  const __bf16* gB1 = W + (size_t)(bn + srow + 64) * Kdim + ke;
  __bf16* lA0 = As + tid * 8;
  __bf16* lA1 = As + (tid + 256) * 8;
  __bf16* lB0 = Bs + tid * 8;
  __bf16* lB1 = Bs + (tid + 256) * 8;

  f32x4 acc[4][4];
#pragma unroll
  for (int i = 0; i < 4; ++i)
#pragma unroll
    for (int j = 0; j < 4; ++j) acc[i][j] = (f32x4)0.0f;

  for (int k0 = 0; k0 < Kdim; k0 += 32) {
    __syncthreads();
    load_lds16(gA0 + k0, lA0);
    load_lds16(gA1 + k0, lA1);
    load_lds16(gB0 + k0, lB0);
    load_lds16(gB1 + k0, lB1);
    __syncthreads();
    bf16x8 af[4], bf[4];
#pragma unroll
    for (int i = 0; i < 4; ++i)
      af[i] = *(const bf16x8*)(As + (wy + i * 16 + mrow) * 32 + quad * 8);
#pragma unroll
    for (int j = 0; j < 4; ++j)
      bf[j] = *(const bf16x8*)(Bs + (wx + j * 16 + mrow) * 32 + quad * 8);
#pragma unroll
    for (int i = 0; i < 4; ++i)
#pragma unroll
      for (int j = 0; j < 4; ++j)
        acc[i][j] = __builtin_amdgcn_mfma_f32_16x16x32_bf16(af[i], bf[j], acc[i][j], 0, 0, 0);
  }

#pragma unroll
  for (int j = 0; j < 4; ++j) {
    int col = bn + wx + j * 16 + mrow;
    float bc = bias[col];
#pragma unroll
    for (int i = 0; i < 4; ++i) {
      int rbase = bm + wy + i * 16 + quad * 4;
#pragma unroll
      for (int r = 0; r < 4; ++r)
        C[(size_t)(rbase + r) * Ndim + col] = (TO)(acc[i][j][r] + bc);
    }
  }
}

// All four projection GEMMs in one dispatch; z picks {q,k1,k2,v}.
__global__ __launch_bounds__(256) void proj_gemm4(
    const __bf16* __restrict__ xbase, const __bf16* __restrict__ wbase,
    const float* __restrict__ bin, __bf16* __restrict__ cbase)
{
  __shared__ __bf16 As[128 * 32];
  __shared__ __bf16 Bs[128 * 32];
  const int z = blockIdx.z;
  const __bf16* X = xbase + ((z == 0) ? 0 : (z == 3) ? 2 * P4S : P4S);
  const __bf16* W = wbase + (size_t)z * P1S;
  const float* bias = bin + z * E_DIM;
  __bf16* C = cbase + (size_t)z * P4S;
  gemm_body<__bf16>(X, W, bias, C, blockIdx.x * 128, blockIdx.y * 128,
                    E_DIM, E_DIM, As, Bs);
}

// Output projection (f32 out).
__global__ __launch_bounds__(256) void out_gemm(
    const __bf16* __restrict__ X, const __bf16* __restrict__ W,
    const float* __restrict__ bias, float* __restrict__ C)
{
  __shared__ __bf16 As[128 * 32];
  __shared__ __bf16 Bs[128 * 32];
  gemm_body<float>(X, W, bias, C, blockIdx.x * 128, blockIdx.y * 128,
                   E_DIM, E_DIM, As, Bs);
}

// ----------------------------------------------------- per-head row norms (f32)
__global__ __launch_bounds__(256) void head_norms(
    const __bf16* __restrict__ Qp, const __bf16* __restrict__ K1p,
    const __bf16* __restrict__ K2p, float* __restrict__ qn,
    float* __restrict__ kn1, float* __restrict__ kn2)
{
  int id = blockIdx.x * 256 + threadIdx.x;     // 0..196607
  int which = id >> 16;
  int r = id & 65535;
  int bh = r >> 10, t = r & 1023;
  int b = bh >> 4, h = bh & 15;
  const __bf16* src = (which == 0) ? Qp : ((which == 1) ? K1p : K2p);
  float* dst = (which == 0) ? qn : ((which == 1) ? kn1 : kn2);
  const __bf16* p = src + (size_t)(t * 4 + b) * 1024 + h * 64;
  float s = 0.f;
#pragma unroll
  for (int c = 0; c < 8; ++c) {
    bf16x8 v = *(const bf16x8*)(p + c * 8);
#pragma unroll
    for (int j = 0; j < 8; ++j) { float x = (float)v[j]; s += x * x; }
  }
  dst[bh * 1024 + t] = s;
}

// -------------------------------------- V transpose: Vp(T,B,E) -> Vt_g[bh][d][u]
// u within each 64-key tile is sigma-permuted: Vt_g[bh][d][kt*64+u] = V[kt*64+sigma(u)][d],
// sigma(u) = (u&3)*16 + (u>>2).
__global__ __launch_bounds__(256) void v_transpose(
    const __bf16* __restrict__ Vp, __bf16* __restrict__ Vt_g)
{
  const int bh = blockIdx.x, kt = blockIdx.y;
  const int b = bh >> 4, h = bh & 15;
  const int tid = threadIdx.x;
  __shared__ __bf16 tile[64][88];   // 176 B rows: 16B-aligned, conflict-mild
  {
    int s = tid >> 2, d0 = (tid & 3) * 16;
    const __bf16* src = Vp + (size_t)((kt * 64 + s) * 4 + b) * 1024 + h * 64 + d0;
    *(bf16x8*)(&tile[s][d0])     = *(const bf16x8*)(src);
    *(bf16x8*)(&tile[s][d0 + 8]) = *(const bf16x8*)(src + 8);
  }
  __syncthreads();
#pragma unroll
  for (int c = 0; c < 2; ++c) {
    int idx = tid * 2 + c;
    int d = idx >> 3, u0 = (idx & 7) * 8;
    bf16x8 o;
#pragma unroll
    for (int i = 0; i < 8; ++i) {
      int u = u0 + i;
      int s = (u & 3) * 16 + (u >> 2);
      o[i] = tile[s][d];
    }
    *(bf16x8*)(Vt_g + ((size_t)bh * 64 + d) * 1024 + kt * 64 + u0) = o;
  }
}

// -------------------------------------------------------- MFMA flash attention
// block = (bh, qt): 64 q-rows; 4 waves x 16 q-rows. 64-key tiles.
// Q fragments hoisted to registers (loop-invariant); no Qs LDS.
// LDS tiles: 64-col rows, XOR chunk swizzle phys_chunk = lc ^ (row&7).
// Key axis of Pl and Vt both sigma-permuted (consistent; sum order-invariant).
// Pl is wave-private -> no barrier between Pl write and read (per-wave LDS
// ops execute in order); 2 barriers per key tile.
__global__ __launch_bounds__(256, 4) void mgk_attn_mfma(
    const __bf16* __restrict__ Qp, const __bf16* __restrict__ K1p,
    const __bf16* __restrict__ K2p, const __bf16* __restrict__ Vt_g,
    const float* __restrict__ qn_g, const float* __restrict__ kn1_g,
    const float* __restrict__ kn2_g, const float* __restrict__ pi,
    __bf16* __restrict__ AO)
{
  __shared__ __bf16 lds[16384];          // 32 KB -> 4 blocks/CU
  __bf16* K1s = lds;                     // 64x64
  __bf16* K2s = lds + 4096;              // 64x64
  __bf16* Vt  = lds + 8192;              // 64(d) x 64(u)
  __bf16* Pl  = lds + 12288;             // 4 waves x 16(q) x 64(u)

  const int bh = blockIdx.x, qt = blockIdx.y;
  const int b = bh >> 4, h = bh & 15;
  const int tid = threadIdx.x, lane = tid & 63, w = tid >> 6;
  const int mrow = lane & 15, quad = lane >> 4;

  // exp folded into exp2: arg = L*acc - cl*(qn + kn), cl = c*log2e, L = 2*cl
  const float cl1 = 0.0625f * 1.4426950408889634f;   // (scaling/2)*log2e
  const float cl2 = 0.1875f * 1.4426950408889634f;   // (3*scaling/2)*log2e
  const float L1 = 2.0f * cl1, L2 = 2.0f * cl2;
  const float p1 = fminf(fmaxf(fabsf(pi[h]), 1e-6f), 2.0f);
  const float p2 = fminf(fmaxf(fabsf(pi[H_DIM + h]), 1e-6f), 2.0f);
  const int hoff = h * 64;

  // Q fragments straight from global (loop-invariant): row = qt*64+w*16+mrow,
  // k-cols = kk*32 + quad*8 .. +8
  bf16x8 af[2];
  {
    const __bf16* qp = Qp + (size_t)((qt * 64 + w * 16 + mrow) * 4 + b) * 1024
                       + hoff + quad * 8;
    af[0] = *(const bf16x8*)(qp);
    af[1] = *(const bf16x8*)(qp + 32);
  }
  f32x4 qnv = *(const f32x4*)(qn_g + bh * 1024 + qt * 64 + w * 16 + quad * 4);
  f32x4 ncq1, ncq2;
#pragma unroll
  for (int r = 0; r < 4; ++r) { ncq1[r] = -cl1 * qnv[r]; ncq2[r] = -cl2 * qnv[r]; }

  f32x4 oacc[4];
#pragma unroll
  for (int j = 0; j < 4; ++j) oacc[j] = (f32x4)0.0f;
  f32x4 rsl = (f32x4)0.0f;

  for (int kt = 0; kt < 16; ++kt) {
    __syncthreads();                               // A: prev PV reads done
    // stage K1,K2,Vt (all async, swizzled)
#pragma unroll
    for (int wi = 0; wi < 2; ++wi) {
      int window = w * 2 + wi;
      int kr = window * 8 + (lane >> 3), c = lane & 7;
      size_t srow = (size_t)((kt * 64 + kr) * 4 + b) * 1024 + hoff;
      int off = (c ^ (kr & 7)) << 3;
      load_lds16(K1p + srow + off, K1s + window * 512 + lane * 8);
      load_lds16(K2p + srow + off, K2s + window * 512 + lane * 8);
      load_lds16(Vt_g + ((size_t)bh * 64 + kr) * 1024 + kt * 64 + off,
                 Vt + window * 512 + lane * 8);
    }
    // key norms for this tile
    float kn1j[4], kn2j[4];
#pragma unroll
    for (int j = 0; j < 4; ++j) {
      kn1j[j] = kn1_g[bh * 1024 + kt * 64 + j * 16 + mrow];
      kn2j[j] = kn2_g[bh * 1024 + kt * 64 + j * 16 + mrow];
    }
    __syncthreads();                               // B: K1s/K2s/Vt ready

    // ---- S1, S2 via MFMA ----
    f32x4 acc1[4], acc2[4];
#pragma unroll
    for (int j = 0; j < 4; ++j) { acc1[j] = (f32x4)0.0f; acc2[j] = (f32x4)0.0f; }
#pragma unroll
    for (int kk = 0; kk < 2; ++kk)
#pragma unroll
      for (int j = 0; j < 4; ++j) {
        bf16x8 b1f = *(const bf16x8*)(K1s + (j * 16 + mrow) * 64
                                      + (((kk * 4 + quad) ^ (mrow & 7)) << 3));
        bf16x8 b2f = *(const bf16x8*)(K2s + (j * 16 + mrow) * 64
                                      + (((kk * 4 + quad) ^ (mrow & 7)) << 3));
        acc1[j] = __builtin_amdgcn_mfma_f32_16x16x32_bf16(af[kk], b1f, acc1[j], 0, 0, 0);
        acc2[j] = __builtin_amdgcn_mfma_f32_16x16x32_bf16(af[kk], b2f, acc2[j], 0, 0, 0);
      }

    // ---- P = p1*exp2(L1*acc1 + nb1) + p2*exp2(L2*acc2 + nb2); Pl (sigma order)
    f32x4 pv[4];
#pragma unroll
    for (int j = 0; j < 4; ++j) {
      f32x4 p;
#pragma unroll
      for (int r = 0; r < 4; ++r) {
        float e1 = __builtin_amdgcn_exp2f(fmaf(L1, acc1[j][r], fmaf(-cl1, kn1j[j], ncq1[r])));
        float e2 = __builtin_amdgcn_exp2f(fmaf(L2, acc2[j][r], fmaf(-cl2, kn2j[j], ncq2[r])));
        p[r] = fmaf(p2, e2, p1 * e1);
      }
      pv[j] = p;
      rsl += p;
    }
#pragma unroll
    for (int r = 0; r < 4; ++r) {
      int q = quad * 4 + r;                        // wave-local row
      bf16x4 pk;
      pk[0] = (__bf16)pv[0][r]; pk[1] = (__bf16)pv[1][r];
      pk[2] = (__bf16)pv[2][r]; pk[3] = (__bf16)pv[3][r];
      int lc = mrow >> 1;
      *(bf16x4*)(Pl + w * 1024 + q * 64 + ((lc ^ (q & 7)) << 3) + (mrow & 1) * 4) = pk;
    }
    // Pl is wave-private; per-wave LDS ops are in-order -> no barrier needed.

    // ---- O += P * V ----
    bf16x8 pf[2];
#pragma unroll
    for (int kk = 0; kk < 2; ++kk)
      pf[kk] = *(const bf16x8*)(Pl + w * 1024 + mrow * 64
                                + (((kk * 4 + quad) ^ (mrow & 7)) << 3));
#pragma unroll
    for (int kk = 0; kk < 2; ++kk)
#pragma unroll
      for (int j = 0; j < 4; ++j) {
        bf16x8 vf = *(const bf16x8*)(Vt + (j * 16 + mrow) * 64
                                     + (((kk * 4 + quad) ^ (mrow & 7)) << 3));
        oacc[j] = __builtin_amdgcn_mfma_f32_16x16x32_bf16(pf[kk], vf, oacc[j], 0, 0, 0);
      }
  }

  // rowsum butterfly across 16 lanes (mrow)
#pragma unroll
  for (int d = 1; d < 16; d <<= 1) {
    f32x4 o;
#pragma unroll
    for (int r = 0; r < 4; ++r) o[r] = __shfl_xor(rsl[r], d, 64);
    rsl += o;
  }

  // normalize + write AO (M,E) bf16
  f32x4 inv;
#pragma unroll
  for (int r = 0; r < 4; ++r) inv[r] = 1.0f / (rsl[r] + 1e-6f);
#pragma unroll
  for (int j = 0; j < 4; ++j) {
    int col = hoff + j * 16 + mrow;
#pragma unroll
    for (int r = 0; r < 4; ++r) {
      int t = qt * 64 + w * 16 + quad * 4 + r;
      AO[(size_t)(t * 4 + b) * 1024 + col] = (__bf16)(oacc[j][r] * inv[r]);
    }
  }
}

extern "C" void kernel_launch(void* const* d_in, const int* in_sizes, int n_in,
                              void* d_out, int out_size, void* d_ws, size_t ws_size,
                              hipStream_t stream) {
  const float* query = (const float*)d_in[0];
  const float* key   = (const float*)d_in[1];
  const float* value = (const float*)d_in[2];
  const float* Wq    = (const float*)d_in[3];
  const float* Wk1   = (const float*)d_in[4];
  const float* Wk2   = (const float*)d_in[5];
  const float* Wv    = (const float*)d_in[6];
  const float* bin   = (const float*)d_in[7];
  const float* Wo    = (const float*)d_in[8];
  const float* bo    = (const float*)d_in[9];
  const float* pi    = (const float*)d_in[10];
  float* out = (float*)d_out;

  __bf16* qc  = (__bf16*)d_ws;          // 3*P4: qc|kc|vc
  __bf16* wq  = qc  + 3 * P4S;          // 5*P1: wq|wk1|wk2|wv|wo
  __bf16* wo  = wq  + 4 * P1S;
  __bf16* Qp  = wq  + 5 * P1S;          // 4*P4: Qp|K1p|K2p|Vp
  __bf16* K1p = Qp  + P4S;
  __bf16* K2p = K1p + P4S;
  __bf16* Vp  = K2p + P4S;
  __bf16* AO  = Vp  + P4S;
  float*  qn_g  = (float*)(AO + P4S);
  float*  kn1_g = qn_g  + 64 * 1024;
  float*  kn2_g = kn1_g + 64 * 1024;
  __bf16* Vt_g  = qc;                   // reuse: qc dead after proj_gemm4

  // 1 conversion dispatch: 3*P4 + 5*P1 = 17825792 elems / 8 per thread
  cvt_all<<<8704, 256, 0, stream>>>(query, key, value, Wq, Wk1, Wk2, Wv, Wo, qc);

  // 4 projections in one dispatch (1024 blocks)
  proj_gemm4<<<dim3(M_DIM / 128, E_DIM / 128, 4), 256, 0, stream>>>(qc, wq, bin, Qp);

  head_norms<<<768, 256, 0, stream>>>(Qp, K1p, K2p, qn_g, kn1_g, kn2_g);
  v_transpose<<<dim3(64, 16), 256, 0, stream>>>(Vp, Vt_g);

  // 64 q-rows per block -> 1024 blocks -> 4 blocks/CU (32 KB LDS each)
  mgk_attn_mfma<<<dim3(64, 16), 256, 0, stream>>>(
      Qp, K1p, K2p, Vt_g, qn_g, kn1_g, kn2_g, pi, AO);

  out_gemm<<<dim3(M_DIM / 128, E_DIM / 128), 256, 0, stream>>>(AO, wo, bo, out);
}

// Round 2
// 261.272 us; speedup vs baseline: 1.0349x; 1.0349x over previous
//
#include <hip/hip_runtime.h>
#include <hip/hip_bf16.h>

#define T_DIM 1024
#define B_DIM 4
#define E_DIM 1024
#define H_DIM 16
#define HD    64
#define M_DIM (T_DIM * B_DIM)   // 4096

typedef __hip_bfloat16 bf16;
typedef __bf16 bf16x8 __attribute__((ext_vector_type(8)));
typedef __bf16 bf16x4 __attribute__((ext_vector_type(4)));
typedef float  f32x4  __attribute__((ext_vector_type(4)));

#define P4S ((size_t)M_DIM * E_DIM)   // 4194304
#define P1S ((size_t)E_DIM * E_DIM)   // 1048576

// ------------------------------------------- fused f32 -> bf16 (all 8 buffers)
__global__ __launch_bounds__(256) void cvt_all(
    const float* __restrict__ q, const float* __restrict__ k,
    const float* __restrict__ v, const float* __restrict__ w0,
    const float* __restrict__ w1, const float* __restrict__ w2,
    const float* __restrict__ w3, const float* __restrict__ w4,
    __bf16* __restrict__ dst)
{
  size_t i = ((size_t)blockIdx.x * 256 + threadIdx.x) * 8;
  const float* src;
  size_t off;
  if (i < P4S)            { src = q; off = i; }
  else if (i < 2 * P4S)   { src = k; off = i - P4S; }
  else if (i < 3 * P4S)   { src = v; off = i - 2 * P4S; }
  else {
    size_t j = i - 3 * P4S;
    int wsel = (int)(j >> 20);          // /P1S
    off = j & (P1S - 1);
    const float* ws[5] = {w0, w1, w2, w3, w4};
    src = ws[wsel];
  }
  float4 a = *(const float4*)(src + off);
  float4 b = *(const float4*)(src + off + 4);
  bf16x8 o;
  o[0] = (__bf16)a.x; o[1] = (__bf16)a.y; o[2] = (__bf16)a.z; o[3] = (__bf16)a.w;
  o[4] = (__bf16)b.x; o[5] = (__bf16)b.y; o[6] = (__bf16)b.z; o[7] = (__bf16)b.w;
  *(bf16x8*)(dst + i) = o;
}

// ------------------------------------------------- async global->LDS, 16 B/lane
__device__ __forceinline__ void load_lds16(const __bf16* g, __bf16* l) {
  __builtin_amdgcn_global_load_lds(
      (__attribute__((address_space(1))) void*)(void*)g,
      (__attribute__((address_space(3))) void*)l, 16, 0, 0);
}

// =======================================================================
// 256x256 8-phase GEMM (BK=64, 8 waves, dbuf LDS, counted vmcnt, swizzle)
// C = X * W^T + bias ; X:(4096,1024) W:(1024,1024) row-major (W rows = N)
// Half-tile numbering: H = 4*T + h, h: 0=A rows0-127, 1=A rows128-255,
//                                      2=B rows0-127, 3=B rows128-255.
// LDS layout per buffer: [256][64] bf16, 16B chunk c stored at pc = c ^ (row&7)
// (global source pre-swizzled; global_load_lds dest stays linear).
// =======================================================================
__device__ __forceinline__ void stage_half(
    int H, const __bf16* __restrict__ X, const __bf16* __restrict__ W,
    int bm, int bn, __bf16* As, __bf16* Bs, int tid)
{
  if (H >= 64) return;                 // K=1024 -> 16 tiles -> 64 half-tiles
  const int T  = H >> 2;
  const int h  = H & 3;
  const int rh = (h & 1) * 128;
  const __bf16* src = (h < 2) ? X : W;
  const int rbase   = (h < 2) ? bm : bn;
  __bf16* lb = ((h < 2) ? As : Bs) + (T & 1) * 16384;
#pragma unroll
  for (int li = 0; li < 2; ++li) {
    int r  = rh + li * 64 + (tid >> 3);          // row within 256-row tile
    int gc = (tid & 7) ^ (r & 7);                // pre-swizzled source chunk
    load_lds16(src + (size_t)(rbase + r) * E_DIM + T * 64 + gc * 8,
               lb + (rh + li * 64) * 64 + tid * 8);   // linear dest
  }
}

// swizzled ds_read of one 16B fragment chunk
#define RD(base, row, c) \
  (*(const bf16x8*)((base) + (row) * 64 + ((((c) ^ ((row) & 7))) << 3)))

__global__ __launch_bounds__(512, 2) void proj_gemm4(
    const __bf16* __restrict__ xbase, const __bf16* __restrict__ wbase,
    const float* __restrict__ bin, __bf16* __restrict__ cbase)
{
  __shared__ __bf16 lds[65536];        // 128 KiB: As[2][256][64] | Bs[2][256][64]
  __bf16* As = lds;
  __bf16* Bs = lds + 32768;

  const int z = blockIdx.z;
  const __bf16* X = xbase + ((z == 0) ? 0 : (z == 3) ? 2 * P4S : P4S);
  const __bf16* W = wbase + (size_t)z * P1S;
  const float* bias = bin + z * E_DIM;
  __bf16* C = cbase + (size_t)z * P4S;

  const int bm = blockIdx.x * 256;
  const int bn = blockIdx.y * 256;

  const int tid  = threadIdx.x;
  const int lane = tid & 63;
  const int w    = tid >> 6;           // 8 waves
  const int wm   = w >> 2;             // 0..1 -> 128 rows each
  const int wn   = w & 3;              // 0..3 -> 64 cols each
  const int mrow = lane & 15, quad = lane >> 4;

  f32x4 acc[8][4];
#pragma unroll
  for (int m = 0; m < 8; ++m)
#pragma unroll
    for (int n = 0; n < 4; ++n) acc[m][n] = (f32x4)0.0f;

  // prologue: tile 0 fully + tile 1 half 0  (10 loads/thread in flight)
#pragma unroll
  for (int H = 0; H < 5; ++H) stage_half(H, X, W, bm, bn, As, Bs, tid);
  asm volatile("s_waitcnt vmcnt(2)" ::: "memory");   // tile-0 halves landed
  __builtin_amdgcn_s_barrier();

  bf16x8 af[4][2];    // A frags for current 64-row m-half
  bf16x8 bq[4][2];    // B frags for all 4 n-blocks (whole K-tile)

#pragma unroll 2
  for (int t = 0; t < 16; ++t) {
    const __bf16* Ab = As + (t & 1) * 16384;
    const __bf16* Bb = Bs + (t & 1) * 16384;

    // ---------------- phase 0: read bq[n0,1], af(m-half 0); MFMA m0-3 x n0-1
#pragma unroll
    for (int n = 0; n < 2; ++n)
#pragma unroll
      for (int kk = 0; kk < 2; ++kk)
        bq[n][kk] = RD(Bb, wn * 64 + n * 16 + mrow, kk * 4 + quad);
#pragma unroll
    for (int m = 0; m < 4; ++m)
#pragma unroll
      for (int kk = 0; kk < 2; ++kk)
        af[m][kk] = RD(Ab, wm * 128 + m * 16 + mrow, kk * 4 + quad);
    stage_half(4 * t + 5, X, W, bm, bn, As, Bs, tid);
    __builtin_amdgcn_s_barrier();
    asm volatile("s_waitcnt lgkmcnt(0)" ::: "memory");
    __builtin_amdgcn_s_setprio(1);
#pragma unroll
    for (int kk = 0; kk < 2; ++kk)
#pragma unroll
      for (int n = 0; n < 2; ++n)
#pragma unroll
        for (int m = 0; m < 4; ++m)
          acc[m][n] = __builtin_amdgcn_mfma_f32_16x16x32_bf16(
              af[m][kk], bq[n][kk], acc[m][n], 0, 0, 0);
    __builtin_amdgcn_s_setprio(0);
    __builtin_amdgcn_s_barrier();

    // ---------------- phase 1: read bq[n2,3]; MFMA m0-3 x n2-3
#pragma unroll
    for (int n = 2; n < 4; ++n)
#pragma unroll
      for (int kk = 0; kk < 2; ++kk)
        bq[n][kk] = RD(Bb, wn * 64 + n * 16 + mrow, kk * 4 + quad);
    stage_half(4 * t + 6, X, W, bm, bn, As, Bs, tid);
    __builtin_amdgcn_s_barrier();
    asm volatile("s_waitcnt lgkmcnt(0)" ::: "memory");
    __builtin_amdgcn_s_setprio(1);
#pragma unroll
    for (int kk = 0; kk < 2; ++kk)
#pragma unroll
      for (int n = 2; n < 4; ++n)
#pragma unroll
        for (int m = 0; m < 4; ++m)
          acc[m][n] = __builtin_amdgcn_mfma_f32_16x16x32_bf16(
              af[m][kk], bq[n][kk], acc[m][n], 0, 0, 0);
    __builtin_amdgcn_s_setprio(0);
    __builtin_amdgcn_s_barrier();

    // ---------------- phase 2: read af(m-half 1); MFMA m4-7 x n0-1
#pragma unroll
    for (int m = 0; m < 4; ++m)
#pragma unroll
      for (int kk = 0; kk < 2; ++kk)
        af[m][kk] = RD(Ab, wm * 128 + 64 + m * 16 + mrow, kk * 4 + quad);
    stage_half(4 * t + 7, X, W, bm, bn, As, Bs, tid);
    __builtin_amdgcn_s_barrier();
    asm volatile("s_waitcnt lgkmcnt(0)" ::: "memory");
    __builtin_amdgcn_s_setprio(1);
#pragma unroll
    for (int kk = 0; kk < 2; ++kk)
#pragma unroll
      for (int n = 0; n < 2; ++n)
#pragma unroll
        for (int m = 0; m < 4; ++m)
          acc[4 + m][n] = __builtin_amdgcn_mfma_f32_16x16x32_bf16(
              af[m][kk], bq[n][kk], acc[4 + m][n], 0, 0, 0);
    __builtin_amdgcn_s_setprio(0);
    __builtin_amdgcn_s_barrier();

    // ---------------- phase 3: MFMA m4-7 x n2-3; counted vmcnt at tile end
    stage_half(4 * t + 8, X, W, bm, bn, As, Bs, tid);
    __builtin_amdgcn_s_barrier();
    __builtin_amdgcn_s_setprio(1);
#pragma unroll
    for (int kk = 0; kk < 2; ++kk)
#pragma unroll
      for (int n = 2; n < 4; ++n)
#pragma unroll
        for (int m = 0; m < 4; ++m)
          acc[4 + m][n] = __builtin_amdgcn_mfma_f32_16x16x32_bf16(
              af[m][kk], bq[n][kk], acc[4 + m][n], 0, 0, 0);
    __builtin_amdgcn_s_setprio(0);
    if (t < 14)       { asm volatile("s_waitcnt vmcnt(2)" ::: "memory"); }
    else if (t == 14) { asm volatile("s_waitcnt vmcnt(0)" ::: "memory"); }
    __builtin_amdgcn_s_barrier();
  }

  // epilogue
#pragma unroll
  for (int n = 0; n < 4; ++n) {
    int col = bn + wn * 64 + n * 16 + mrow;
    float bc = bias[col];
#pragma unroll
    for (int m = 0; m < 8; ++m) {
      int rbase = bm + wm * 128 + m * 16 + quad * 4;
#pragma unroll
      for (int r = 0; r < 4; ++r)
        C[(size_t)(rbase + r) * E_DIM + col] = (__bf16)(acc[m][n][r] + bc);
    }
  }
}

// --------------------------------------------------- GEMM core (128x128, BK=32)
template <typename TO>
__device__ __forceinline__ void gemm_body(
    const __bf16* __restrict__ X, const __bf16* __restrict__ W,
    const float* __restrict__ bias, TO* __restrict__ C,
    int bm, int bn, int Ndim, int Kdim, __bf16* As, __bf16* Bs)
{
  const int tid  = threadIdx.x;
  const int lane = tid & 63;
  const int wave = tid >> 6;
  const int wy = (wave >> 1) * 64;
  const int wx = (wave & 1) * 64;
  const int mrow = lane & 15, quad = lane >> 4;

  const int srow = tid >> 2;
  const int ke   = (tid & 3) * 8;
  const __bf16* gA0 = X + (size_t)(bm + srow)      * Kdim + ke;
  const __bf16* gA1 = X + (size_t)(bm + srow + 64) * Kdim + ke;
  const __bf16* gB0 = W + (size_t)(bn + srow)      * Kdim + ke;
  const __bf16* gB1 = W + (size_t)(bn + srow + 64) * Kdim + ke;
  __bf16* lA0 = As + tid * 8;
  __bf16* lA1 = As + (tid + 256) * 8;
  __bf16* lB0 = Bs + tid * 8;
  __bf16* lB1 = Bs + (tid + 256) * 8;

  f32x4 acc[4][4];
#pragma unroll
  for (int i = 0; i < 4; ++i)
#pragma unroll
    for (int j = 0; j < 4; ++j) acc[i][j] = (f32x4)0.0f;

  for (int k0 = 0; k0 < Kdim; k0 += 32) {
    __syncthreads();
    load_lds16(gA0 + k0, lA0);
    load_lds16(gA1 + k0, lA1);
    load_lds16(gB0 + k0, lB0);
    load_lds16(gB1 + k0, lB1);
    __syncthreads();
    bf16x8 af[4], bf[4];
#pragma unroll
    for (int i = 0; i < 4; ++i)
      af[i] = *(const bf16x8*)(As + (wy + i * 16 + mrow) * 32 + quad * 8);
#pragma unroll
    for (int j = 0; j < 4; ++j)
      bf[j] = *(const bf16x8*)(Bs + (wx + j * 16 + mrow) * 32 + quad * 8);
#pragma unroll
    for (int i = 0; i < 4; ++i)
#pragma unroll
      for (int j = 0; j < 4; ++j)
        acc[i][j] = __builtin_amdgcn_mfma_f32_16x16x32_bf16(af[i], bf[j], acc[i][j], 0, 0, 0);
  }

#pragma unroll
  for (int j = 0; j < 4; ++j) {
    int col = bn + wx + j * 16 + mrow;
    float bc = bias[col];
#pragma unroll
    for (int i = 0; i < 4; ++i) {
      int rbase = bm + wy + i * 16 + quad * 4;
#pragma unroll
      for (int r = 0; r < 4; ++r)
        C[(size_t)(rbase + r) * Ndim + col] = (TO)(acc[i][j][r] + bc);
    }
  }
}

// Output projection (f32 out).
__global__ __launch_bounds__(256) void out_gemm(
    const __bf16* __restrict__ X, const __bf16* __restrict__ W,
    const float* __restrict__ bias, float* __restrict__ C)
{
  __shared__ __bf16 As[128 * 32];
  __shared__ __bf16 Bs[128 * 32];
  gemm_body<float>(X, W, bias, C, blockIdx.x * 128, blockIdx.y * 128,
                   E_DIM, E_DIM, As, Bs);
}

// ----------------------------------------------------- per-head row norms (f32)
__global__ __launch_bounds__(256) void head_norms(
    const __bf16* __restrict__ Qp, const __bf16* __restrict__ K1p,
    const __bf16* __restrict__ K2p, float* __restrict__ qn,
    float* __restrict__ kn1, float* __restrict__ kn2)
{
  int id = blockIdx.x * 256 + threadIdx.x;     // 0..196607
  int which = id >> 16;
  int r = id & 65535;
  int bh = r >> 10, t = r & 1023;
  int b = bh >> 4, h = bh & 15;
  const __bf16* src = (which == 0) ? Qp : ((which == 1) ? K1p : K2p);
  float* dst = (which == 0) ? qn : ((which == 1) ? kn1 : kn2);
  const __bf16* p = src + (size_t)(t * 4 + b) * 1024 + h * 64;
  float s = 0.f;
#pragma unroll
  for (int c = 0; c < 8; ++c) {
    bf16x8 v = *(const bf16x8*)(p + c * 8);
#pragma unroll
    for (int j = 0; j < 8; ++j) { float x = (float)v[j]; s += x * x; }
  }
  dst[bh * 1024 + t] = s;
}

// -------------------------------------- V transpose: Vp(T,B,E) -> Vt_g[bh][d][u]
__global__ __launch_bounds__(256) void v_transpose(
    const __bf16* __restrict__ Vp, __bf16* __restrict__ Vt_g)
{
  const int bh = blockIdx.x, kt = blockIdx.y;
  const int b = bh >> 4, h = bh & 15;
  const int tid = threadIdx.x;
  __shared__ __bf16 tile[64][88];   // 176 B rows: 16B-aligned, conflict-mild
  {
    int s = tid >> 2, d0 = (tid & 3) * 16;
    const __bf16* src = Vp + (size_t)((kt * 64 + s) * 4 + b) * 1024 + h * 64 + d0;
    *(bf16x8*)(&tile[s][d0])     = *(const bf16x8*)(src);
    *(bf16x8*)(&tile[s][d0 + 8]) = *(const bf16x8*)(src + 8);
  }
  __syncthreads();
#pragma unroll
  for (int c = 0; c < 2; ++c) {
    int idx = tid * 2 + c;
    int d = idx >> 3, u0 = (idx & 7) * 8;
    bf16x8 o;
#pragma unroll
    for (int i = 0; i < 8; ++i) {
      int u = u0 + i;
      int s = (u & 3) * 16 + (u >> 2);
      o[i] = tile[s][d];
    }
    *(bf16x8*)(Vt_g + ((size_t)bh * 64 + d) * 1024 + kt * 64 + u0) = o;
  }
}

// -------------------------------------------------------- MFMA flash attention
__global__ __launch_bounds__(256, 4) void mgk_attn_mfma(
    const __bf16* __restrict__ Qp, const __bf16* __restrict__ K1p,
    const __bf16* __restrict__ K2p, const __bf16* __restrict__ Vt_g,
    const float* __restrict__ qn_g, const float* __restrict__ kn1_g,
    const float* __restrict__ kn2_g, const float* __restrict__ pi,
    __bf16* __restrict__ AO)
{
  __shared__ __bf16 lds[16384];          // 32 KB -> 4 blocks/CU
  __bf16* K1s = lds;                     // 64x64
  __bf16* K2s = lds + 4096;              // 64x64
  __bf16* Vt  = lds + 8192;              // 64(d) x 64(u)
  __bf16* Pl  = lds + 12288;             // 4 waves x 16(q) x 64(u)

  const int bh = blockIdx.x, qt = blockIdx.y;
  const int b = bh >> 4, h = bh & 15;
  const int tid = threadIdx.x, lane = tid & 63, w = tid >> 6;
  const int mrow = lane & 15, quad = lane >> 4;

  const float cl1 = 0.0625f * 1.4426950408889634f;   // (scaling/2)*log2e
  const float cl2 = 0.1875f * 1.4426950408889634f;   // (3*scaling/2)*log2e
  const float L1 = 2.0f * cl1, L2 = 2.0f * cl2;
  const float p1 = fminf(fmaxf(fabsf(pi[h]), 1e-6f), 2.0f);
  const float p2 = fminf(fmaxf(fabsf(pi[H_DIM + h]), 1e-6f), 2.0f);
  const int hoff = h * 64;

  bf16x8 af[2];
  {
    const __bf16* qp = Qp + (size_t)((qt * 64 + w * 16 + mrow) * 4 + b) * 1024
                       + hoff + quad * 8;
    af[0] = *(const bf16x8*)(qp);
    af[1] = *(const bf16x8*)(qp + 32);
  }
  f32x4 qnv = *(const f32x4*)(qn_g + bh * 1024 + qt * 64 + w * 16 + quad * 4);
  f32x4 ncq1, ncq2;
#pragma unroll
  for (int r = 0; r < 4; ++r) { ncq1[r] = -cl1 * qnv[r]; ncq2[r] = -cl2 * qnv[r]; }

  f32x4 oacc[4];
#pragma unroll
  for (int j = 0; j < 4; ++j) oacc[j] = (f32x4)0.0f;
  f32x4 rsl = (f32x4)0.0f;

  for (int kt = 0; kt < 16; ++kt) {
    __syncthreads();                               // A: prev PV reads done
#pragma unroll
    for (int wi = 0; wi < 2; ++wi) {
      int window = w * 2 + wi;
      int kr = window * 8 + (lane >> 3), c = lane & 7;
      size_t srow = (size_t)((kt * 64 + kr) * 4 + b) * 1024 + hoff;
      int off = (c ^ (kr & 7)) << 3;
      load_lds16(K1p + srow + off, K1s + window * 512 + lane * 8);
      load_lds16(K2p + srow + off, K2s + window * 512 + lane * 8);
      load_lds16(Vt_g + ((size_t)bh * 64 + kr) * 1024 + kt * 64 + off,
                 Vt + window * 512 + lane * 8);
    }
    float kn1j[4], kn2j[4];
#pragma unroll
    for (int j = 0; j < 4; ++j) {
      kn1j[j] = kn1_g[bh * 1024 + kt * 64 + j * 16 + mrow];
      kn2j[j] = kn2_g[bh * 1024 + kt * 64 + j * 16 + mrow];
    }
    __syncthreads();                               // B: K1s/K2s/Vt ready

    f32x4 acc1[4], acc2[4];
#pragma unroll
    for (int j = 0; j < 4; ++j) { acc1[j] = (f32x4)0.0f; acc2[j] = (f32x4)0.0f; }
#pragma unroll
    for (int kk = 0; kk < 2; ++kk)
#pragma unroll
      for (int j = 0; j < 4; ++j) {
        bf16x8 b1f = *(const bf16x8*)(K1s + (j * 16 + mrow) * 64
                                      + (((kk * 4 + quad) ^ (mrow & 7)) << 3));
        bf16x8 b2f = *(const bf16x8*)(K2s + (j * 16 + mrow) * 64
                                      + (((kk * 4 + quad) ^ (mrow & 7)) << 3));
        acc1[j] = __builtin_amdgcn_mfma_f32_16x16x32_bf16(af[kk], b1f, acc1[j], 0, 0, 0);
        acc2[j] = __builtin_amdgcn_mfma_f32_16x16x32_bf16(af[kk], b2f, acc2[j], 0, 0, 0);
      }

    f32x4 pv[4];
#pragma unroll
    for (int j = 0; j < 4; ++j) {
      f32x4 p;
#pragma unroll
      for (int r = 0; r < 4; ++r) {
        float e1 = __builtin_amdgcn_exp2f(fmaf(L1, acc1[j][r], fmaf(-cl1, kn1j[j], ncq1[r])));
        float e2 = __builtin_amdgcn_exp2f(fmaf(L2, acc2[j][r], fmaf(-cl2, kn2j[j], ncq2[r])));
        p[r] = fmaf(p2, e2, p1 * e1);
      }
      pv[j] = p;
      rsl += p;
    }
#pragma unroll
    for (int r = 0; r < 4; ++r) {
      int q = quad * 4 + r;                        // wave-local row
      bf16x4 pk;
      pk[0] = (__bf16)pv[0][r]; pk[1] = (__bf16)pv[1][r];
      pk[2] = (__bf16)pv[2][r]; pk[3] = (__bf16)pv[3][r];
      int lc = mrow >> 1;
      *(bf16x4*)(Pl + w * 1024 + q * 64 + ((lc ^ (q & 7)) << 3) + (mrow & 1) * 4) = pk;
    }

    bf16x8 pf[2];
#pragma unroll
    for (int kk = 0; kk < 2; ++kk)
      pf[kk] = *(const bf16x8*)(Pl + w * 1024 + mrow * 64
                                + (((kk * 4 + quad) ^ (mrow & 7)) << 3));
#pragma unroll
    for (int kk = 0; kk < 2; ++kk)
#pragma unroll
      for (int j = 0; j < 4; ++j) {
        bf16x8 vf = *(const bf16x8*)(Vt + (j * 16 + mrow) * 64
                                     + (((kk * 4 + quad) ^ (mrow & 7)) << 3));
        oacc[j] = __builtin_amdgcn_mfma_f32_16x16x32_bf16(pf[kk], vf, oacc[j], 0, 0, 0);
      }
  }

#pragma unroll
  for (int d = 1; d < 16; d <<= 1) {
    f32x4 o;
#pragma unroll
    for (int r = 0; r < 4; ++r) o[r] = __shfl_xor(rsl[r], d, 64);
    rsl += o;
  }

  f32x4 inv;
#pragma unroll
  for (int r = 0; r < 4; ++r) inv[r] = 1.0f / (rsl[r] + 1e-6f);
#pragma unroll
  for (int j = 0; j < 4; ++j) {
    int col = hoff + j * 16 + mrow;
#pragma unroll
    for (int r = 0; r < 4; ++r) {
      int t = qt * 64 + w * 16 + quad * 4 + r;
      AO[(size_t)(t * 4 + b) * 1024 + col] = (__bf16)(oacc[j][r] * inv[r]);
    }
  }
}

extern "C" void kernel_launch(void* const* d_in, const int* in_sizes, int n_in,
                              void* d_out, int out_size, void* d_ws, size_t ws_size,
                              hipStream_t stream) {
  const float* query = (const float*)d_in[0];
  const float* key   = (const float*)d_in[1];
  const float* value = (const float*)d_in[2];
  const float* Wq    = (const float*)d_in[3];
  const float* Wk1   = (const float*)d_in[4];
  const float* Wk2   = (const float*)d_in[5];
  const float* Wv    = (const float*)d_in[6];
  const float* bin   = (const float*)d_in[7];
  const float* Wo    = (const float*)d_in[8];
  const float* bo    = (const float*)d_in[9];
  const float* pi    = (const float*)d_in[10];
  float* out = (float*)d_out;

  __bf16* qc  = (__bf16*)d_ws;          // 3*P4: qc|kc|vc
  __bf16* wq  = qc  + 3 * P4S;          // 5*P1: wq|wk1|wk2|wv|wo
  __bf16* wo  = wq  + 4 * P1S;
  __bf16* Qp  = wq  + 5 * P1S;          // 4*P4: Qp|K1p|K2p|Vp
  __bf16* K1p = Qp  + P4S;
  __bf16* K2p = K1p + P4S;
  __bf16* Vp  = K2p + P4S;
  __bf16* AO  = Vp  + P4S;
  float*  qn_g  = (float*)(AO + P4S);
  float*  kn1_g = qn_g  + 64 * 1024;
  float*  kn2_g = kn1_g + 64 * 1024;
  __bf16* Vt_g  = qc;                   // reuse: qc dead after proj_gemm4

  cvt_all<<<8704, 256, 0, stream>>>(query, key, value, Wq, Wk1, Wk2, Wv, Wo, qc);

  // 4 projections, 256x256 tiles: grid 16x4x4 = 256 blocks = 1 block/CU
  proj_gemm4<<<dim3(M_DIM / 256, E_DIM / 256, 4), 512, 0, stream>>>(qc, wq, bin, Qp);

  head_norms<<<768, 256, 0, stream>>>(Qp, K1p, K2p, qn_g, kn1_g, kn2_g);
  v_transpose<<<dim3(64, 16), 256, 0, stream>>>(Vp, Vt_g);

  mgk_attn_mfma<<<dim3(64, 16), 256, 0, stream>>>(
      Qp, K1p, K2p, Vt_g, qn_g, kn1_g, kn2_g, pi, AO);

  out_gemm<<<dim3(M_DIM / 128, E_DIM / 128), 256, 0, stream>>>(AO, wo, bo, out);
}

// Round 3
// 257.901 us; speedup vs baseline: 1.0484x; 1.0131x over previous
//
#include <hip/hip_runtime.h>
#include <hip/hip_bf16.h>

#define T_DIM 1024
#define B_DIM 4
#define E_DIM 1024
#define H_DIM 16
#define HD    64
#define M_DIM (T_DIM * B_DIM)   // 4096

typedef __hip_bfloat16 bf16;
typedef __bf16 bf16x8 __attribute__((ext_vector_type(8)));
typedef __bf16 bf16x4 __attribute__((ext_vector_type(4)));
typedef float  f32x4  __attribute__((ext_vector_type(4)));

#define P4S ((size_t)M_DIM * E_DIM)   // 4194304
#define P1S ((size_t)E_DIM * E_DIM)   // 1048576

// ------------------------------------------- fused f32 -> bf16 (all 8 buffers)
__global__ __launch_bounds__(256) void cvt_all(
    const float* __restrict__ q, const float* __restrict__ k,
    const float* __restrict__ v, const float* __restrict__ w0,
    const float* __restrict__ w1, const float* __restrict__ w2,
    const float* __restrict__ w3, const float* __restrict__ w4,
    __bf16* __restrict__ dst)
{
  size_t i = ((size_t)blockIdx.x * 256 + threadIdx.x) * 8;
  const float* src;
  size_t off;
  if (i < P4S)            { src = q; off = i; }
  else if (i < 2 * P4S)   { src = k; off = i - P4S; }
  else if (i < 3 * P4S)   { src = v; off = i - 2 * P4S; }
  else {
    size_t j = i - 3 * P4S;
    int wsel = (int)(j >> 20);          // /P1S
    off = j & (P1S - 1);
    const float* ws[5] = {w0, w1, w2, w3, w4};
    src = ws[wsel];
  }
  float4 a = *(const float4*)(src + off);
  float4 b = *(const float4*)(src + off + 4);
  bf16x8 o;
  o[0] = (__bf16)a.x; o[1] = (__bf16)a.y; o[2] = (__bf16)a.z; o[3] = (__bf16)a.w;
  o[4] = (__bf16)b.x; o[5] = (__bf16)b.y; o[6] = (__bf16)b.z; o[7] = (__bf16)b.w;
  *(bf16x8*)(dst + i) = o;
}

// ------------------------------------------------- async global->LDS, 16 B/lane
__device__ __forceinline__ void load_lds16(const __bf16* g, __bf16* l) {
  __builtin_amdgcn_global_load_lds(
      (__attribute__((address_space(1))) void*)(void*)g,
      (__attribute__((address_space(3))) void*)l, 16, 0, 0);
}

// =======================================================================
// 256x256 8-phase GEMM (BK=64, 8 waves, dbuf LDS, counted vmcnt, swizzle)
// =======================================================================
__device__ __forceinline__ void stage_half(
    int H, const __bf16* __restrict__ X, const __bf16* __restrict__ W,
    int bm, int bn, __bf16* As, __bf16* Bs, int tid)
{
  if (H >= 64) return;                 // K=1024 -> 16 tiles -> 64 half-tiles
  const int T  = H >> 2;
  const int h  = H & 3;
  const int rh = (h & 1) * 128;
  const __bf16* src = (h < 2) ? X : W;
  const int rbase   = (h < 2) ? bm : bn;
  __bf16* lb = ((h < 2) ? As : Bs) + (T & 1) * 16384;
#pragma unroll
  for (int li = 0; li < 2; ++li) {
    int r  = rh + li * 64 + (tid >> 3);          // row within 256-row tile
    int gc = (tid & 7) ^ (r & 7);                // pre-swizzled source chunk
    load_lds16(src + (size_t)(rbase + r) * E_DIM + T * 64 + gc * 8,
               lb + (rh + li * 64) * 64 + tid * 8);   // linear dest
  }
}

#define RD(base, row, c) \
  (*(const bf16x8*)((base) + (row) * 64 + ((((c) ^ ((row) & 7))) << 3)))

__global__ __launch_bounds__(512, 2) void proj_gemm4(
    const __bf16* __restrict__ xbase, const __bf16* __restrict__ wbase,
    const float* __restrict__ bin, __bf16* __restrict__ cbase)
{
  __shared__ __bf16 lds[65536];        // 128 KiB
  __bf16* As = lds;
  __bf16* Bs = lds + 32768;

  const int z = blockIdx.z;
  const __bf16* X = xbase + ((z == 0) ? 0 : (z == 3) ? 2 * P4S : P4S);
  const __bf16* W = wbase + (size_t)z * P1S;
  const float* bias = bin + z * E_DIM;
  __bf16* C = cbase + (size_t)z * P4S;

  const int bm = blockIdx.x * 256;
  const int bn = blockIdx.y * 256;

  const int tid  = threadIdx.x;
  const int lane = tid & 63;
  const int w    = tid >> 6;           // 8 waves
  const int wm   = w >> 2;
  const int wn   = w & 3;
  const int mrow = lane & 15, quad = lane >> 4;

  f32x4 acc[8][4];
#pragma unroll
  for (int m = 0; m < 8; ++m)
#pragma unroll
    for (int n = 0; n < 4; ++n) acc[m][n] = (f32x4)0.0f;

#pragma unroll
  for (int H = 0; H < 5; ++H) stage_half(H, X, W, bm, bn, As, Bs, tid);
  asm volatile("s_waitcnt vmcnt(2)" ::: "memory");
  __builtin_amdgcn_s_barrier();

  bf16x8 af[4][2];
  bf16x8 bq[4][2];

#pragma unroll 2
  for (int t = 0; t < 16; ++t) {
    const __bf16* Ab = As + (t & 1) * 16384;
    const __bf16* Bb = Bs + (t & 1) * 16384;

    // phase 0
#pragma unroll
    for (int n = 0; n < 2; ++n)
#pragma unroll
      for (int kk = 0; kk < 2; ++kk)
        bq[n][kk] = RD(Bb, wn * 64 + n * 16 + mrow, kk * 4 + quad);
#pragma unroll
    for (int m = 0; m < 4; ++m)
#pragma unroll
      for (int kk = 0; kk < 2; ++kk)
        af[m][kk] = RD(Ab, wm * 128 + m * 16 + mrow, kk * 4 + quad);
    stage_half(4 * t + 5, X, W, bm, bn, As, Bs, tid);
    __builtin_amdgcn_s_barrier();
    asm volatile("s_waitcnt lgkmcnt(0)" ::: "memory");
    __builtin_amdgcn_s_setprio(1);
#pragma unroll
    for (int kk = 0; kk < 2; ++kk)
#pragma unroll
      for (int n = 0; n < 2; ++n)
#pragma unroll
        for (int m = 0; m < 4; ++m)
          acc[m][n] = __builtin_amdgcn_mfma_f32_16x16x32_bf16(
              af[m][kk], bq[n][kk], acc[m][n], 0, 0, 0);
    __builtin_amdgcn_s_setprio(0);
    __builtin_amdgcn_s_barrier();

    // phase 1
#pragma unroll
    for (int n = 2; n < 4; ++n)
#pragma unroll
      for (int kk = 0; kk < 2; ++kk)
        bq[n][kk] = RD(Bb, wn * 64 + n * 16 + mrow, kk * 4 + quad);
    stage_half(4 * t + 6, X, W, bm, bn, As, Bs, tid);
    __builtin_amdgcn_s_barrier();
    asm volatile("s_waitcnt lgkmcnt(0)" ::: "memory");
    __builtin_amdgcn_s_setprio(1);
#pragma unroll
    for (int kk = 0; kk < 2; ++kk)
#pragma unroll
      for (int n = 2; n < 4; ++n)
#pragma unroll
        for (int m = 0; m < 4; ++m)
          acc[m][n] = __builtin_amdgcn_mfma_f32_16x16x32_bf16(
              af[m][kk], bq[n][kk], acc[m][n], 0, 0, 0);
    __builtin_amdgcn_s_setprio(0);
    __builtin_amdgcn_s_barrier();

    // phase 2
#pragma unroll
    for (int m = 0; m < 4; ++m)
#pragma unroll
      for (int kk = 0; kk < 2; ++kk)
        af[m][kk] = RD(Ab, wm * 128 + 64 + m * 16 + mrow, kk * 4 + quad);
    stage_half(4 * t + 7, X, W, bm, bn, As, Bs, tid);
    __builtin_amdgcn_s_barrier();
    asm volatile("s_waitcnt lgkmcnt(0)" ::: "memory");
    __builtin_amdgcn_s_setprio(1);
#pragma unroll
    for (int kk = 0; kk < 2; ++kk)
#pragma unroll
      for (int n = 0; n < 2; ++n)
#pragma unroll
        for (int m = 0; m < 4; ++m)
          acc[4 + m][n] = __builtin_amdgcn_mfma_f32_16x16x32_bf16(
              af[m][kk], bq[n][kk], acc[4 + m][n], 0, 0, 0);
    __builtin_amdgcn_s_setprio(0);
    __builtin_amdgcn_s_barrier();

    // phase 3
    stage_half(4 * t + 8, X, W, bm, bn, As, Bs, tid);
    __builtin_amdgcn_s_barrier();
    __builtin_amdgcn_s_setprio(1);
#pragma unroll
    for (int kk = 0; kk < 2; ++kk)
#pragma unroll
      for (int n = 2; n < 4; ++n)
#pragma unroll
        for (int m = 0; m < 4; ++m)
          acc[4 + m][n] = __builtin_amdgcn_mfma_f32_16x16x32_bf16(
              af[m][kk], bq[n][kk], acc[4 + m][n], 0, 0, 0);
    __builtin_amdgcn_s_setprio(0);
    if (t < 14)       { asm volatile("s_waitcnt vmcnt(2)" ::: "memory"); }
    else if (t == 14) { asm volatile("s_waitcnt vmcnt(0)" ::: "memory"); }
    __builtin_amdgcn_s_barrier();
  }

#pragma unroll
  for (int n = 0; n < 4; ++n) {
    int col = bn + wn * 64 + n * 16 + mrow;
    float bc = bias[col];
#pragma unroll
    for (int m = 0; m < 8; ++m) {
      int rbase = bm + wm * 128 + m * 16 + quad * 4;
#pragma unroll
      for (int r = 0; r < 4; ++r)
        C[(size_t)(rbase + r) * E_DIM + col] = (__bf16)(acc[m][n][r] + bc);
    }
  }
}

// --------------------------------------------------- GEMM core (128x128, BK=32)
template <typename TO>
__device__ __forceinline__ void gemm_body(
    const __bf16* __restrict__ X, const __bf16* __restrict__ W,
    const float* __restrict__ bias, TO* __restrict__ C,
    int bm, int bn, int Ndim, int Kdim, __bf16* As, __bf16* Bs)
{
  const int tid  = threadIdx.x;
  const int lane = tid & 63;
  const int wave = tid >> 6;
  const int wy = (wave >> 1) * 64;
  const int wx = (wave & 1) * 64;
  const int mrow = lane & 15, quad = lane >> 4;

  const int srow = tid >> 2;
  const int ke   = (tid & 3) * 8;
  const __bf16* gA0 = X + (size_t)(bm + srow)      * Kdim + ke;
  const __bf16* gA1 = X + (size_t)(bm + srow + 64) * Kdim + ke;
  const __bf16* gB0 = W + (size_t)(bn + srow)      * Kdim + ke;
  const __bf16* gB1 = W + (size_t)(bn + srow + 64) * Kdim + ke;
  __bf16* lA0 = As + tid * 8;
  __bf16* lA1 = As + (tid + 256) * 8;
  __bf16* lB0 = Bs + tid * 8;
  __bf16* lB1 = Bs + (tid + 256) * 8;

  f32x4 acc[4][4];
#pragma unroll
  for (int i = 0; i < 4; ++i)
#pragma unroll
    for (int j = 0; j < 4; ++j) acc[i][j] = (f32x4)0.0f;

  for (int k0 = 0; k0 < Kdim; k0 += 32) {
    __syncthreads();
    load_lds16(gA0 + k0, lA0);
    load_lds16(gA1 + k0, lA1);
    load_lds16(gB0 + k0, lB0);
    load_lds16(gB1 + k0, lB1);
    __syncthreads();
    bf16x8 af[4], bf[4];
#pragma unroll
    for (int i = 0; i < 4; ++i)
      af[i] = *(const bf16x8*)(As + (wy + i * 16 + mrow) * 32 + quad * 8);
#pragma unroll
    for (int j = 0; j < 4; ++j)
      bf[j] = *(const bf16x8*)(Bs + (wx + j * 16 + mrow) * 32 + quad * 8);
#pragma unroll
    for (int i = 0; i < 4; ++i)
#pragma unroll
      for (int j = 0; j < 4; ++j)
        acc[i][j] = __builtin_amdgcn_mfma_f32_16x16x32_bf16(af[i], bf[j], acc[i][j], 0, 0, 0);
  }

#pragma unroll
  for (int j = 0; j < 4; ++j) {
    int col = bn + wx + j * 16 + mrow;
    float bc = bias[col];
#pragma unroll
    for (int i = 0; i < 4; ++i) {
      int rbase = bm + wy + i * 16 + quad * 4;
#pragma unroll
      for (int r = 0; r < 4; ++r)
        C[(size_t)(rbase + r) * Ndim + col] = (TO)(acc[i][j][r] + bc);
    }
  }
}

// Output projection (f32 out).
__global__ __launch_bounds__(256) void out_gemm(
    const __bf16* __restrict__ X, const __bf16* __restrict__ W,
    const float* __restrict__ bias, float* __restrict__ C)
{
  __shared__ __bf16 As[128 * 32];
  __shared__ __bf16 Bs[128 * 32];
  gemm_body<float>(X, W, bias, C, blockIdx.x * 128, blockIdx.y * 128,
                   E_DIM, E_DIM, As, Bs);
}

// ------------------------- merged: per-head row norms + V transpose (1 dispatch)
// blocks [0,768): norms. blocks [768, 768+1024): V transpose.
__global__ __launch_bounds__(256) void norms_vt(
    const __bf16* __restrict__ Qp, const __bf16* __restrict__ K1p,
    const __bf16* __restrict__ K2p, const __bf16* __restrict__ Vp,
    float* __restrict__ qn, float* __restrict__ kn1, float* __restrict__ kn2,
    __bf16* __restrict__ Vt_g)
{
  __shared__ __bf16 tile[64][88];
  const int tid = threadIdx.x;
  if (blockIdx.x < 768) {
    int id = blockIdx.x * 256 + tid;           // 0..196607
    int which = id >> 16;
    int r = id & 65535;
    int bh = r >> 10, t = r & 1023;
    int b = bh >> 4, h = bh & 15;
    const __bf16* src = (which == 0) ? Qp : ((which == 1) ? K1p : K2p);
    float* dst = (which == 0) ? qn : ((which == 1) ? kn1 : kn2);
    const __bf16* p = src + (size_t)(t * 4 + b) * 1024 + h * 64;
    float s = 0.f;
#pragma unroll
    for (int c = 0; c < 8; ++c) {
      bf16x8 v = *(const bf16x8*)(p + c * 8);
#pragma unroll
      for (int j = 0; j < 8; ++j) { float x = (float)v[j]; s += x * x; }
    }
    dst[bh * 1024 + t] = s;
    return;
  }
  // ---- V transpose: Vt_g[bh][d][kt*64+u] = V[kt*64+sigma(u)][d],
  // sigma(u) = (u&3)*16 + (u>>2).
  int bid = blockIdx.x - 768;
  const int bh = bid & 63, kt = bid >> 6;
  const int b = bh >> 4, h = bh & 15;
  {
    int s = tid >> 2, d0 = (tid & 3) * 16;
    const __bf16* src = Vp + (size_t)((kt * 64 + s) * 4 + b) * 1024 + h * 64 + d0;
    *(bf16x8*)(&tile[s][d0])     = *(const bf16x8*)(src);
    *(bf16x8*)(&tile[s][d0 + 8]) = *(const bf16x8*)(src + 8);
  }
  __syncthreads();
#pragma unroll
  for (int c = 0; c < 2; ++c) {
    int idx = tid * 2 + c;
    int d = idx >> 3, u0 = (idx & 7) * 8;
    bf16x8 o;
#pragma unroll
    for (int i = 0; i < 8; ++i) {
      int u = u0 + i;
      int s = (u & 3) * 16 + (u >> 2);
      o[i] = tile[s][d];
    }
    *(bf16x8*)(Vt_g + ((size_t)bh * 64 + d) * 1024 + kt * 64 + u0) = o;
  }
}

// -------------------------------------------------------- MFMA flash attention
// 64 q-rows/block, 4 waves x 16. Reg-staged prefetch (T14): tile kt+1 loaded
// into VGPRs during compute of kt; ds_write after barrier A. Barrier B is raw
// s_barrier + lgkmcnt(0) (no vmem drain). Row-constant exp(-c1*qn) factored
// out of softmax (cancels in normalization); log2(pi) folded into exponents.
__global__ __launch_bounds__(256, 4) void mgk_attn_mfma(
    const __bf16* __restrict__ Qp, const __bf16* __restrict__ K1p,
    const __bf16* __restrict__ K2p, const __bf16* __restrict__ Vt_g,
    const float* __restrict__ qn_g, const float* __restrict__ kn1_g,
    const float* __restrict__ kn2_g, const float* __restrict__ pi,
    __bf16* __restrict__ AO)
{
  __shared__ __bf16 lds[16384];          // 32 KB -> 4 blocks/CU
  __bf16* K1s = lds;                     // 64x64 (swizzled)
  __bf16* K2s = lds + 4096;              // 64x64
  __bf16* Vt  = lds + 8192;              // 64(d) x 64(u)
  __bf16* Pl  = lds + 12288;             // 4 waves x 16(q) x 64(u)

  const int bh = blockIdx.x, qt = blockIdx.y;
  const int b = bh >> 4, h = bh & 15;
  const int tid = threadIdx.x, lane = tid & 63, w = tid >> 6;
  const int mrow = lane & 15, quad = lane >> 4;

  const float cl1 = 0.0625f * 1.4426950408889634f;   // (scaling/2)*log2e
  const float cl2 = 0.1875f * 1.4426950408889634f;   // (3*scaling/2)*log2e
  const float L1 = 2.0f * cl1, L2 = 2.0f * cl2;
  const float p1 = fminf(fmaxf(fabsf(pi[h]), 1e-6f), 2.0f);
  const float p2 = fminf(fmaxf(fabsf(pi[H_DIM + h]), 1e-6f), 2.0f);
  const float lp1 = __log2f(p1), lp2 = __log2f(p2);
  const int hoff = h * 64;

  // Q fragments (loop-invariant)
  bf16x8 af[2];
  {
    const __bf16* qp = Qp + (size_t)((qt * 64 + w * 16 + mrow) * 4 + b) * 1024
                       + hoff + quad * 8;
    af[0] = *(const bf16x8*)(qp);
    af[1] = *(const bf16x8*)(qp + 32);
  }
  f32x4 qnv = *(const f32x4*)(qn_g + bh * 1024 + qt * 64 + w * 16 + quad * 4);
  f32x4 aq2;                    // per-r: (cl1-cl2)*qn + log2(p2)
#pragma unroll
  for (int r = 0; r < 4; ++r) aq2[r] = fmaf(cl1 - cl2, qnv[r], lp2);

  // staging geometry: wave w stages windows w*2, w*2+1 of K1/K2/Vt
  const int lw = lane >> 3;              // 0..7 row-in-window
  const int c  = lane & 7;               // linear global 16B chunk
  const int dsw  = (c ^ lw) << 3;        // swizzled LDS chunk offset
  const int dstA = (w * 2) * 512 + lw * 64 + dsw;       // rows kr0 = w*16+lw
  const int dstB = (w * 2 + 1) * 512 + lw * 64 + dsw;   // rows kr1 = kr0+8
  const int kr0 = w * 16 + lw, kr1 = kr0 + 8;

  const size_t KSTRIDE = (size_t)64 * 4 * 1024;   // 64 keys per kt
  const __bf16* pk1a = K1p + (size_t)(kr0 * 4 + b) * 1024 + hoff + c * 8;
  const __bf16* pk1b = K1p + (size_t)(kr1 * 4 + b) * 1024 + hoff + c * 8;
  const __bf16* pk2a = K2p + (size_t)(kr0 * 4 + b) * 1024 + hoff + c * 8;
  const __bf16* pk2b = K2p + (size_t)(kr1 * 4 + b) * 1024 + hoff + c * 8;
  const __bf16* pva  = Vt_g + ((size_t)bh * 64 + kr0) * 1024 + c * 8;
  const __bf16* pvb  = Vt_g + ((size_t)bh * 64 + kr1) * 1024 + c * 8;
  const float*  pn1  = kn1_g + bh * 1024 + mrow;
  const float*  pn2  = kn2_g + bh * 1024 + mrow;

  bf16x8 fk1a, fk1b, fk2a, fk2b, fva, fvb;
  float fn1[4], fn2[4];
  // prefetch kt=0
  fk1a = *(const bf16x8*)pk1a; fk1b = *(const bf16x8*)pk1b;
  fk2a = *(const bf16x8*)pk2a; fk2b = *(const bf16x8*)pk2b;
  fva  = *(const bf16x8*)pva;  fvb  = *(const bf16x8*)pvb;
#pragma unroll
  for (int j = 0; j < 4; ++j) { fn1[j] = pn1[j * 16]; fn2[j] = pn2[j * 16]; }

  f32x4 oacc[4];
#pragma unroll
  for (int j = 0; j < 4; ++j) oacc[j] = (f32x4)0.0f;
  f32x4 rsl = (f32x4)0.0f;

  for (int kt = 0; kt < 16; ++kt) {
    __syncthreads();           // A: prev compute reads done; pf loads are old
    // commit prefetched tile to LDS (swizzled dest)
    *(bf16x8*)(K1s + dstA) = fk1a;  *(bf16x8*)(K1s + dstB) = fk1b;
    *(bf16x8*)(K2s + dstA) = fk2a;  *(bf16x8*)(K2s + dstB) = fk2b;
    *(bf16x8*)(Vt  + dstA) = fva;   *(bf16x8*)(Vt  + dstB) = fvb;
    // per-tile softmax constants from prefetched norms (before overwrite)
    float nb1[4], s2[4];
#pragma unroll
    for (int j = 0; j < 4; ++j) {
      nb1[j] = fmaf(-cl1, fn1[j], lp1);
      s2[j]  = -cl2 * fn2[j];
    }
    if (kt < 15) {             // issue next tile's loads (complete during compute)
      pk1a += KSTRIDE; pk1b += KSTRIDE; pk2a += KSTRIDE; pk2b += KSTRIDE;
      pva += 64; pvb += 64; pn1 += 64; pn2 += 64;
      fk1a = *(const bf16x8*)pk1a; fk1b = *(const bf16x8*)pk1b;
      fk2a = *(const bf16x8*)pk2a; fk2b = *(const bf16x8*)pk2b;
      fva  = *(const bf16x8*)pva;  fvb  = *(const bf16x8*)pvb;
#pragma unroll
      for (int j = 0; j < 4; ++j) { fn1[j] = pn1[j * 16]; fn2[j] = pn2[j * 16]; }
    }
    asm volatile("s_waitcnt lgkmcnt(0)" ::: "memory");
    __builtin_amdgcn_s_barrier();   // B: LDS tile visible to all waves

    // ---- S1, S2 via MFMA ----
    f32x4 acc1[4], acc2[4];
#pragma unroll
    for (int j = 0; j < 4; ++j) { acc1[j] = (f32x4)0.0f; acc2[j] = (f32x4)0.0f; }
#pragma unroll
    for (int kk = 0; kk < 2; ++kk)
#pragma unroll
      for (int j = 0; j < 4; ++j) {
        bf16x8 b1f = *(const bf16x8*)(K1s + (j * 16 + mrow) * 64
                                      + (((kk * 4 + quad) ^ (mrow & 7)) << 3));
        bf16x8 b2f = *(const bf16x8*)(K2s + (j * 16 + mrow) * 64
                                      + (((kk * 4 + quad) ^ (mrow & 7)) << 3));
        acc1[j] = __builtin_amdgcn_mfma_f32_16x16x32_bf16(af[kk], b1f, acc1[j], 0, 0, 0);
        acc2[j] = __builtin_amdgcn_mfma_f32_16x16x32_bf16(af[kk], b2f, acc2[j], 0, 0, 0);
      }

    // ---- P' = exp2(L1*S1 + nb1[j]) + exp2(L2*S2 + s2[j] + aq2[r]) ----
    // (row factor 2^(cl1*qn) dropped; cancels in normalization)
    f32x4 pv[4];
#pragma unroll
    for (int j = 0; j < 4; ++j) {
      f32x4 p;
#pragma unroll
      for (int r = 0; r < 4; ++r) {
        float e1 = __builtin_amdgcn_exp2f(fmaf(L1, acc1[j][r], nb1[j]));
        float e2 = __builtin_amdgcn_exp2f(fmaf(L2, acc2[j][r], s2[j] + aq2[r]));
        p[r] = e1 + e2;
      }
      pv[j] = p;
      rsl += p;
    }
#pragma unroll
    for (int r = 0; r < 4; ++r) {
      int q = quad * 4 + r;                        // wave-local row
      bf16x4 pk;
      pk[0] = (__bf16)pv[0][r]; pk[1] = (__bf16)pv[1][r];
      pk[2] = (__bf16)pv[2][r]; pk[3] = (__bf16)pv[3][r];
      int lc = mrow >> 1;
      *(bf16x4*)(Pl + w * 1024 + q * 64 + ((lc ^ (q & 7)) << 3) + (mrow & 1) * 4) = pk;
    }
    // Pl is wave-private; per-wave LDS ops are in-order -> no barrier needed.

    // ---- O += P * V ----
    bf16x8 pf[2];
#pragma unroll
    for (int kk = 0; kk < 2; ++kk)
      pf[kk] = *(const bf16x8*)(Pl + w * 1024 + mrow * 64
                                + (((kk * 4 + quad) ^ (mrow & 7)) << 3));
#pragma unroll
    for (int kk = 0; kk < 2; ++kk)
#pragma unroll
      for (int j = 0; j < 4; ++j) {
        bf16x8 vf = *(const bf16x8*)(Vt + (j * 16 + mrow) * 64
                                     + (((kk * 4 + quad) ^ (mrow & 7)) << 3));
        oacc[j] = __builtin_amdgcn_mfma_f32_16x16x32_bf16(pf[kk], vf, oacc[j], 0, 0, 0);
      }
  }

  // rowsum butterfly across 16 lanes (mrow)
#pragma unroll
  for (int d = 1; d < 16; d <<= 1) {
    f32x4 o;
#pragma unroll
    for (int r = 0; r < 4; ++r) o[r] = __shfl_xor(rsl[r], d, 64);
    rsl += o;
  }

  f32x4 inv;
#pragma unroll
  for (int r = 0; r < 4; ++r) inv[r] = 1.0f / (rsl[r] + 1e-6f);
#pragma unroll
  for (int j = 0; j < 4; ++j) {
    int col = hoff + j * 16 + mrow;
#pragma unroll
    for (int r = 0; r < 4; ++r) {
      int t = qt * 64 + w * 16 + quad * 4 + r;
      AO[(size_t)(t * 4 + b) * 1024 + col] = (__bf16)(oacc[j][r] * inv[r]);
    }
  }
}

extern "C" void kernel_launch(void* const* d_in, const int* in_sizes, int n_in,
                              void* d_out, int out_size, void* d_ws, size_t ws_size,
                              hipStream_t stream) {
  const float* query = (const float*)d_in[0];
  const float* key   = (const float*)d_in[1];
  const float* value = (const float*)d_in[2];
  const float* Wq    = (const float*)d_in[3];
  const float* Wk1   = (const float*)d_in[4];
  const float* Wk2   = (const float*)d_in[5];
  const float* Wv    = (const float*)d_in[6];
  const float* bin   = (const float*)d_in[7];
  const float* Wo    = (const float*)d_in[8];
  const float* bo    = (const float*)d_in[9];
  const float* pi    = (const float*)d_in[10];
  float* out = (float*)d_out;

  __bf16* qc  = (__bf16*)d_ws;          // 3*P4: qc|kc|vc
  __bf16* wq  = qc  + 3 * P4S;          // 5*P1: wq|wk1|wk2|wv|wo
  __bf16* wo  = wq  + 4 * P1S;
  __bf16* Qp  = wq  + 5 * P1S;          // 4*P4: Qp|K1p|K2p|Vp
  __bf16* K1p = Qp  + P4S;
  __bf16* K2p = K1p + P4S;
  __bf16* Vp  = K2p + P4S;
  __bf16* AO  = Vp  + P4S;
  float*  qn_g  = (float*)(AO + P4S);
  float*  kn1_g = qn_g  + 64 * 1024;
  float*  kn2_g = kn1_g + 64 * 1024;
  __bf16* Vt_g  = qc;                   // reuse: qc dead after proj_gemm4

  cvt_all<<<8704, 256, 0, stream>>>(query, key, value, Wq, Wk1, Wk2, Wv, Wo, qc);

  // 4 projections, 256x256 tiles: grid 16x4x4 = 256 blocks = 1 block/CU
  proj_gemm4<<<dim3(M_DIM / 256, E_DIM / 256, 4), 512, 0, stream>>>(qc, wq, bin, Qp);

  // merged norms + V transpose (one dispatch)
  norms_vt<<<768 + 1024, 256, 0, stream>>>(Qp, K1p, K2p, Vp,
                                           qn_g, kn1_g, kn2_g, Vt_g);

  mgk_attn_mfma<<<dim3(64, 16), 256, 0, stream>>>(
      Qp, K1p, K2p, Vt_g, qn_g, kn1_g, kn2_g, pi, AO);

  out_gemm<<<dim3(M_DIM / 128, E_DIM / 128), 256, 0, stream>>>(AO, wo, bo, out);
}

// Round 4
// 238.319 us; speedup vs baseline: 1.1346x; 1.0822x over previous
//
#include <hip/hip_runtime.h>
#include <hip/hip_bf16.h>

#define T_DIM 1024
#define B_DIM 4
#define E_DIM 1024
#define H_DIM 16
#define HD    64
#define M_DIM (T_DIM * B_DIM)   // 4096

typedef __hip_bfloat16 bf16;
typedef __bf16 bf16x8 __attribute__((ext_vector_type(8)));
typedef __bf16 bf16x4 __attribute__((ext_vector_type(4)));
typedef float  f32x4  __attribute__((ext_vector_type(4)));

#define P4S ((size_t)M_DIM * E_DIM)   // 4194304
#define P1S ((size_t)E_DIM * E_DIM)   // 1048576

// ------------------------------------------- fused f32 -> bf16 (all 8 buffers)
__global__ __launch_bounds__(256) void cvt_all(
    const float* __restrict__ q, const float* __restrict__ k,
    const float* __restrict__ v, const float* __restrict__ w0,
    const float* __restrict__ w1, const float* __restrict__ w2,
    const float* __restrict__ w3, const float* __restrict__ w4,
    __bf16* __restrict__ dst)
{
  size_t i = ((size_t)blockIdx.x * 256 + threadIdx.x) * 8;
  const float* src;
  size_t off;
  if (i < P4S)            { src = q; off = i; }
  else if (i < 2 * P4S)   { src = k; off = i - P4S; }
  else if (i < 3 * P4S)   { src = v; off = i - 2 * P4S; }
  else {
    size_t j = i - 3 * P4S;
    int wsel = (int)(j >> 20);          // /P1S
    off = j & (P1S - 1);
    const float* ws[5] = {w0, w1, w2, w3, w4};
    src = ws[wsel];
  }
  float4 a = *(const float4*)(src + off);
  float4 b = *(const float4*)(src + off + 4);
  bf16x8 o;
  o[0] = (__bf16)a.x; o[1] = (__bf16)a.y; o[2] = (__bf16)a.z; o[3] = (__bf16)a.w;
  o[4] = (__bf16)b.x; o[5] = (__bf16)b.y; o[6] = (__bf16)b.z; o[7] = (__bf16)b.w;
  *(bf16x8*)(dst + i) = o;
}

// ------------------------------------------------- async global->LDS, 16 B/lane
__device__ __forceinline__ void load_lds16(const __bf16* g, __bf16* l) {
  __builtin_amdgcn_global_load_lds(
      (__attribute__((address_space(1))) void*)(void*)g,
      (__attribute__((address_space(3))) void*)l, 16, 0, 0);
}

// =======================================================================
// 256x256 8-phase GEMM (BK=64, 8 waves, dbuf LDS, counted vmcnt, swizzle)
// =======================================================================
__device__ __forceinline__ void stage_half(
    int H, const __bf16* __restrict__ X, const __bf16* __restrict__ W,
    int bm, int bn, __bf16* As, __bf16* Bs, int tid)
{
  if (H >= 64) return;                 // K=1024 -> 16 tiles -> 64 half-tiles
  const int T  = H >> 2;
  const int h  = H & 3;
  const int rh = (h & 1) * 128;
  const __bf16* src = (h < 2) ? X : W;
  const int rbase   = (h < 2) ? bm : bn;
  __bf16* lb = ((h < 2) ? As : Bs) + (T & 1) * 16384;
#pragma unroll
  for (int li = 0; li < 2; ++li) {
    int r  = rh + li * 64 + (tid >> 3);          // row within 256-row tile
    int gc = (tid & 7) ^ (r & 7);                // pre-swizzled source chunk
    load_lds16(src + (size_t)(rbase + r) * E_DIM + T * 64 + gc * 8,
               lb + (rh + li * 64) * 64 + tid * 8);   // linear dest
  }
}

#define RD(base, row, c) \
  (*(const bf16x8*)((base) + (row) * 64 + ((((c) ^ ((row) & 7))) << 3)))

__global__ __launch_bounds__(512, 2) void proj_gemm4(
    const __bf16* __restrict__ xbase, const __bf16* __restrict__ wbase,
    const float* __restrict__ bin, __bf16* __restrict__ cbase)
{
  __shared__ __bf16 lds[65536];        // 128 KiB
  __bf16* As = lds;
  __bf16* Bs = lds + 32768;

  const int z = blockIdx.z;
  const __bf16* X = xbase + ((z == 0) ? 0 : (z == 3) ? 2 * P4S : P4S);
  const __bf16* W = wbase + (size_t)z * P1S;
  const float* bias = bin + z * E_DIM;
  __bf16* C = cbase + (size_t)z * P4S;

  const int bm = blockIdx.x * 256;
  const int bn = blockIdx.y * 256;

  const int tid  = threadIdx.x;
  const int lane = tid & 63;
  const int w    = tid >> 6;           // 8 waves
  const int wm   = w >> 2;
  const int wn   = w & 3;
  const int mrow = lane & 15, quad = lane >> 4;

  f32x4 acc[8][4];
#pragma unroll
  for (int m = 0; m < 8; ++m)
#pragma unroll
    for (int n = 0; n < 4; ++n) acc[m][n] = (f32x4)0.0f;

#pragma unroll
  for (int H = 0; H < 5; ++H) stage_half(H, X, W, bm, bn, As, Bs, tid);
  asm volatile("s_waitcnt vmcnt(2)" ::: "memory");
  __builtin_amdgcn_s_barrier();

  bf16x8 af[4][2];
  bf16x8 bq[4][2];

#pragma unroll 2
  for (int t = 0; t < 16; ++t) {
    const __bf16* Ab = As + (t & 1) * 16384;
    const __bf16* Bb = Bs + (t & 1) * 16384;

    // phase 0
#pragma unroll
    for (int n = 0; n < 2; ++n)
#pragma unroll
      for (int kk = 0; kk < 2; ++kk)
        bq[n][kk] = RD(Bb, wn * 64 + n * 16 + mrow, kk * 4 + quad);
#pragma unroll
    for (int m = 0; m < 4; ++m)
#pragma unroll
      for (int kk = 0; kk < 2; ++kk)
        af[m][kk] = RD(Ab, wm * 128 + m * 16 + mrow, kk * 4 + quad);
    stage_half(4 * t + 5, X, W, bm, bn, As, Bs, tid);
    __builtin_amdgcn_s_barrier();
    asm volatile("s_waitcnt lgkmcnt(0)" ::: "memory");
    __builtin_amdgcn_s_setprio(1);
#pragma unroll
    for (int kk = 0; kk < 2; ++kk)
#pragma unroll
      for (int n = 0; n < 2; ++n)
#pragma unroll
        for (int m = 0; m < 4; ++m)
          acc[m][n] = __builtin_amdgcn_mfma_f32_16x16x32_bf16(
              af[m][kk], bq[n][kk], acc[m][n], 0, 0, 0);
    __builtin_amdgcn_s_setprio(0);
    __builtin_amdgcn_s_barrier();

    // phase 1
#pragma unroll
    for (int n = 2; n < 4; ++n)
#pragma unroll
      for (int kk = 0; kk < 2; ++kk)
        bq[n][kk] = RD(Bb, wn * 64 + n * 16 + mrow, kk * 4 + quad);
    stage_half(4 * t + 6, X, W, bm, bn, As, Bs, tid);
    __builtin_amdgcn_s_barrier();
    asm volatile("s_waitcnt lgkmcnt(0)" ::: "memory");
    __builtin_amdgcn_s_setprio(1);
#pragma unroll
    for (int kk = 0; kk < 2; ++kk)
#pragma unroll
      for (int n = 2; n < 4; ++n)
#pragma unroll
        for (int m = 0; m < 4; ++m)
          acc[m][n] = __builtin_amdgcn_mfma_f32_16x16x32_bf16(
              af[m][kk], bq[n][kk], acc[m][n], 0, 0, 0);
    __builtin_amdgcn_s_setprio(0);
    __builtin_amdgcn_s_barrier();

    // phase 2
#pragma unroll
    for (int m = 0; m < 4; ++m)
#pragma unroll
      for (int kk = 0; kk < 2; ++kk)
        af[m][kk] = RD(Ab, wm * 128 + 64 + m * 16 + mrow, kk * 4 + quad);
    stage_half(4 * t + 7, X, W, bm, bn, As, Bs, tid);
    __builtin_amdgcn_s_barrier();
    asm volatile("s_waitcnt lgkmcnt(0)" ::: "memory");
    __builtin_amdgcn_s_setprio(1);
#pragma unroll
    for (int kk = 0; kk < 2; ++kk)
#pragma unroll
      for (int n = 0; n < 2; ++n)
#pragma unroll
        for (int m = 0; m < 4; ++m)
          acc[4 + m][n] = __builtin_amdgcn_mfma_f32_16x16x32_bf16(
              af[m][kk], bq[n][kk], acc[4 + m][n], 0, 0, 0);
    __builtin_amdgcn_s_setprio(0);
    __builtin_amdgcn_s_barrier();

    // phase 3
    stage_half(4 * t + 8, X, W, bm, bn, As, Bs, tid);
    __builtin_amdgcn_s_barrier();
    __builtin_amdgcn_s_setprio(1);
#pragma unroll
    for (int kk = 0; kk < 2; ++kk)
#pragma unroll
      for (int n = 2; n < 4; ++n)
#pragma unroll
        for (int m = 0; m < 4; ++m)
          acc[4 + m][n] = __builtin_amdgcn_mfma_f32_16x16x32_bf16(
              af[m][kk], bq[n][kk], acc[4 + m][n], 0, 0, 0);
    __builtin_amdgcn_s_setprio(0);
    if (t < 14)       { asm volatile("s_waitcnt vmcnt(2)" ::: "memory"); }
    else if (t == 14) { asm volatile("s_waitcnt vmcnt(0)" ::: "memory"); }
    __builtin_amdgcn_s_barrier();
  }

#pragma unroll
  for (int n = 0; n < 4; ++n) {
    int col = bn + wn * 64 + n * 16 + mrow;
    float bc = bias[col];
#pragma unroll
    for (int m = 0; m < 8; ++m) {
      int rbase = bm + wm * 128 + m * 16 + quad * 4;
#pragma unroll
      for (int r = 0; r < 4; ++r)
        C[(size_t)(rbase + r) * E_DIM + col] = (__bf16)(acc[m][n][r] + bc);
    }
  }
}

// --------------------------------------------------- GEMM core (128x128, BK=32)
template <typename TO>
__device__ __forceinline__ void gemm_body(
    const __bf16* __restrict__ X, const __bf16* __restrict__ W,
    const float* __restrict__ bias, TO* __restrict__ C,
    int bm, int bn, int Ndim, int Kdim, __bf16* As, __bf16* Bs)
{
  const int tid  = threadIdx.x;
  const int lane = tid & 63;
  const int wave = tid >> 6;
  const int wy = (wave >> 1) * 64;
  const int wx = (wave & 1) * 64;
  const int mrow = lane & 15, quad = lane >> 4;

  const int srow = tid >> 2;
  const int ke   = (tid & 3) * 8;
  const __bf16* gA0 = X + (size_t)(bm + srow)      * Kdim + ke;
  const __bf16* gA1 = X + (size_t)(bm + srow + 64) * Kdim + ke;
  const __bf16* gB0 = W + (size_t)(bn + srow)      * Kdim + ke;
  const __bf16* gB1 = W + (size_t)(bn + srow + 64) * Kdim + ke;
  __bf16* lA0 = As + tid * 8;
  __bf16* lA1 = As + (tid + 256) * 8;
  __bf16* lB0 = Bs + tid * 8;
  __bf16* lB1 = Bs + (tid + 256) * 8;

  f32x4 acc[4][4];
#pragma unroll
  for (int i = 0; i < 4; ++i)
#pragma unroll
    for (int j = 0; j < 4; ++j) acc[i][j] = (f32x4)0.0f;

  for (int k0 = 0; k0 < Kdim; k0 += 32) {
    __syncthreads();
    load_lds16(gA0 + k0, lA0);
    load_lds16(gA1 + k0, lA1);
    load_lds16(gB0 + k0, lB0);
    load_lds16(gB1 + k0, lB1);
    __syncthreads();
    bf16x8 af[4], bf[4];
#pragma unroll
    for (int i = 0; i < 4; ++i)
      af[i] = *(const bf16x8*)(As + (wy + i * 16 + mrow) * 32 + quad * 8);
#pragma unroll
    for (int j = 0; j < 4; ++j)
      bf[j] = *(const bf16x8*)(Bs + (wx + j * 16 + mrow) * 32 + quad * 8);
#pragma unroll
    for (int i = 0; i < 4; ++i)
#pragma unroll
      for (int j = 0; j < 4; ++j)
        acc[i][j] = __builtin_amdgcn_mfma_f32_16x16x32_bf16(af[i], bf[j], acc[i][j], 0, 0, 0);
  }

#pragma unroll
  for (int j = 0; j < 4; ++j) {
    int col = bn + wx + j * 16 + mrow;
    float bc = bias[col];
#pragma unroll
    for (int i = 0; i < 4; ++i) {
      int rbase = bm + wy + i * 16 + quad * 4;
#pragma unroll
      for (int r = 0; r < 4; ++r)
        C[(size_t)(rbase + r) * Ndim + col] = (TO)(acc[i][j][r] + bc);
    }
  }
}

// Output projection (f32 out).
__global__ __launch_bounds__(256) void out_gemm(
    const __bf16* __restrict__ X, const __bf16* __restrict__ W,
    const float* __restrict__ bias, float* __restrict__ C)
{
  __shared__ __bf16 As[128 * 32];
  __shared__ __bf16 Bs[128 * 32];
  gemm_body<float>(X, W, bias, C, blockIdx.x * 128, blockIdx.y * 128,
                   E_DIM, E_DIM, As, Bs);
}

// ------------------------- merged: per-head row norms + V transpose (1 dispatch)
__global__ __launch_bounds__(256) void norms_vt(
    const __bf16* __restrict__ Qp, const __bf16* __restrict__ K1p,
    const __bf16* __restrict__ K2p, const __bf16* __restrict__ Vp,
    float* __restrict__ qn, float* __restrict__ kn1, float* __restrict__ kn2,
    __bf16* __restrict__ Vt_g)
{
  __shared__ __bf16 tile[64][88];
  const int tid = threadIdx.x;
  if (blockIdx.x < 768) {
    int id = blockIdx.x * 256 + tid;           // 0..196607
    int which = id >> 16;
    int r = id & 65535;
    int bh = r >> 10, t = r & 1023;
    int b = bh >> 4, h = bh & 15;
    const __bf16* src = (which == 0) ? Qp : ((which == 1) ? K1p : K2p);
    float* dst = (which == 0) ? qn : ((which == 1) ? kn1 : kn2);
    const __bf16* p = src + (size_t)(t * 4 + b) * 1024 + h * 64;
    float s = 0.f;
#pragma unroll
    for (int c = 0; c < 8; ++c) {
      bf16x8 v = *(const bf16x8*)(p + c * 8);
#pragma unroll
      for (int j = 0; j < 8; ++j) { float x = (float)v[j]; s += x * x; }
    }
    dst[bh * 1024 + t] = s;
    return;
  }
  // ---- V transpose: Vt_g[bh][d][kt*64+u] = V[kt*64+sigma(u)][d],
  // sigma(u) = (u&3)*16 + (u>>2).
  int bid = blockIdx.x - 768;
  const int bh = bid & 63, kt = bid >> 6;
  const int b = bh >> 4, h = bh & 15;
  {
    int s = tid >> 2, d0 = (tid & 3) * 16;
    const __bf16* src = Vp + (size_t)((kt * 64 + s) * 4 + b) * 1024 + h * 64 + d0;
    *(bf16x8*)(&tile[s][d0])     = *(const bf16x8*)(src);
    *(bf16x8*)(&tile[s][d0 + 8]) = *(const bf16x8*)(src + 8);
  }
  __syncthreads();
#pragma unroll
  for (int c = 0; c < 2; ++c) {
    int idx = tid * 2 + c;
    int d = idx >> 3, u0 = (idx & 7) * 8;
    bf16x8 o;
#pragma unroll
    for (int i = 0; i < 8; ++i) {
      int u = u0 + i;
      int s = (u & 3) * 16 + (u >> 2);
      o[i] = tile[s][d];
    }
    *(bf16x8*)(Vt_g + ((size_t)bh * 64 + d) * 1024 + kt * 64 + u0) = o;
  }
}

// -------------------------------------------------------- MFMA flash attention
// 8 waves / 512 thr, 128 q-rows per block (wave w owns rows w*16..w*16+15).
// K1/K2/Vt double-buffered in LDS (2 x 24 KB), staged via global_load_lds with
// COUNTED vmcnt(3) (never 0 in steady loop) -- tile kt+2 in flight across the
// whole compute of kt+1. Pl wave-private (16 KB). 64 KB LDS -> 2 blocks/CU.
__global__ __launch_bounds__(512, 4) void mgk_attn_mfma(
    const __bf16* __restrict__ Qp, const __bf16* __restrict__ K1p,
    const __bf16* __restrict__ K2p, const __bf16* __restrict__ Vt_g,
    const float* __restrict__ qn_g, const float* __restrict__ kn1_g,
    const float* __restrict__ kn2_g, const float* __restrict__ pi,
    __bf16* __restrict__ AO)
{
  __shared__ __bf16 lds[32768];          // 64 KB
  // buf q at q*12288: K1s(4096) | K2s(4096) | Vt(4096).  Pl at 24576 (8192).
  __bf16* Pl = lds + 24576;

  const int bh = blockIdx.x, qt = blockIdx.y;
  const int b = bh >> 4, h = bh & 15;
  const int tid = threadIdx.x, lane = tid & 63, w = tid >> 6;
  const int mrow = lane & 15, quad = lane >> 4;

  const float cl1 = 0.0625f * 1.4426950408889634f;   // (scaling/2)*log2e
  const float cl2 = 0.1875f * 1.4426950408889634f;   // (3*scaling/2)*log2e
  const float L1 = 2.0f * cl1, L2 = 2.0f * cl2;
  const float p1 = fminf(fmaxf(fabsf(pi[h]), 1e-6f), 2.0f);
  const float p2 = fminf(fmaxf(fabsf(pi[H_DIM + h]), 1e-6f), 2.0f);
  const float lp1 = __log2f(p1), lp2 = __log2f(p2);
  const int hoff = h * 64;

  // Q fragments (loop-invariant)
  bf16x8 af[2];
  {
    const __bf16* qp = Qp + (size_t)((qt * 128 + w * 16 + mrow) * 4 + b) * 1024
                       + hoff + quad * 8;
    af[0] = *(const bf16x8*)(qp);
    af[1] = *(const bf16x8*)(qp + 32);
  }
  f32x4 qnv = *(const f32x4*)(qn_g + bh * 1024 + qt * 128 + w * 16 + quad * 4);
  f32x4 aq2;                    // per-r: (cl1-cl2)*qn + log2(p2)
#pragma unroll
  for (int r = 0; r < 4; ++r) aq2[r] = fmaf(cl1 - cl2, qnv[r], lp2);

  // staging geometry: thread stages one 16B chunk per buffer region.
  const int srow = tid >> 3;             // 0..63 key-row (or d-row for Vt)
  const int sc   = tid & 7;              // linear LDS chunk
  const int gc   = sc ^ (srow & 7);      // pre-swizzled source chunk
  const int doff = tid * 8;              // linear dest (elems)
  const __bf16* gK1 = K1p + (size_t)(srow * 4 + b) * 1024 + hoff + gc * 8;
  const __bf16* gK2 = K2p + (size_t)(srow * 4 + b) * 1024 + hoff + gc * 8;
  const __bf16* gVt = Vt_g + ((size_t)bh * 64 + srow) * 1024 + gc * 8;

#define STAGE_T(kt_, bsel_) do {                                         \
    __bf16* bb_ = lds + (bsel_) * 12288;                                 \
    load_lds16(gK1 + (size_t)(kt_) * 262144, bb_ + doff);                \
    load_lds16(gK2 + (size_t)(kt_) * 262144, bb_ + 4096 + doff);         \
    load_lds16(gVt + (kt_) * 64,             bb_ + 8192 + doff);         \
  } while (0)

  STAGE_T(0, 0);
  STAGE_T(1, 1);
  asm volatile("s_waitcnt vmcnt(3)" ::: "memory");   // tile 0 landed
  __builtin_amdgcn_s_barrier();
  asm volatile("" ::: "memory");

  f32x4 oacc[4];
#pragma unroll
  for (int j = 0; j < 4; ++j) oacc[j] = (f32x4)0.0f;
  f32x4 rsl = (f32x4)0.0f;

  for (int kt = 0; kt < 16; ++kt) {
    const int cur = kt & 1;
    const __bf16* K1s = lds + cur * 12288;
    const __bf16* K2s = K1s + 4096;
    const __bf16* Vt  = K1s + 8192;

    // per-tile softmax constants
    float nb1[4], s2[4];
#pragma unroll
    for (int j = 0; j < 4; ++j) {
      float f1 = kn1_g[bh * 1024 + kt * 64 + j * 16 + mrow];
      float f2 = kn2_g[bh * 1024 + kt * 64 + j * 16 + mrow];
      nb1[j] = fmaf(-cl1, f1, lp1);
      s2[j]  = -cl2 * f2;
    }

    // ---- S1, S2 via MFMA ----
    f32x4 acc1[4], acc2[4];
#pragma unroll
    for (int j = 0; j < 4; ++j) { acc1[j] = (f32x4)0.0f; acc2[j] = (f32x4)0.0f; }
    __builtin_amdgcn_s_setprio(1);
#pragma unroll
    for (int kk = 0; kk < 2; ++kk)
#pragma unroll
      for (int j = 0; j < 4; ++j) {
        bf16x8 b1f = *(const bf16x8*)(K1s + (j * 16 + mrow) * 64
                                      + (((kk * 4 + quad) ^ (mrow & 7)) << 3));
        bf16x8 b2f = *(const bf16x8*)(K2s + (j * 16 + mrow) * 64
                                      + (((kk * 4 + quad) ^ (mrow & 7)) << 3));
        acc1[j] = __builtin_amdgcn_mfma_f32_16x16x32_bf16(af[kk], b1f, acc1[j], 0, 0, 0);
        acc2[j] = __builtin_amdgcn_mfma_f32_16x16x32_bf16(af[kk], b2f, acc2[j], 0, 0, 0);
      }
    __builtin_amdgcn_s_setprio(0);

    // ---- P' = exp2(L1*S1 + nb1[j]) + exp2(L2*S2 + s2[j] + aq2[r]) ----
    f32x4 pv[4];
#pragma unroll
    for (int j = 0; j < 4; ++j) {
      f32x4 p;
#pragma unroll
      for (int r = 0; r < 4; ++r) {
        float e1 = __builtin_amdgcn_exp2f(fmaf(L1, acc1[j][r], nb1[j]));
        float e2 = __builtin_amdgcn_exp2f(fmaf(L2, acc2[j][r], s2[j] + aq2[r]));
        p[r] = e1 + e2;
      }
      pv[j] = p;
      rsl += p;
    }
#pragma unroll
    for (int r = 0; r < 4; ++r) {
      int q = quad * 4 + r;                        // wave-local row
      bf16x4 pk;
      pk[0] = (__bf16)pv[0][r]; pk[1] = (__bf16)pv[1][r];
      pk[2] = (__bf16)pv[2][r]; pk[3] = (__bf16)pv[3][r];
      int lc = mrow >> 1;
      *(bf16x4*)(Pl + w * 1024 + q * 64 + ((lc ^ (q & 7)) << 3) + (mrow & 1) * 4) = pk;
    }
    // Pl is wave-private; per-wave LDS ops are in-order -> no barrier needed.

    // ---- O += P * V ----
    bf16x8 pf[2];
#pragma unroll
    for (int kk = 0; kk < 2; ++kk)
      pf[kk] = *(const bf16x8*)(Pl + w * 1024 + mrow * 64
                                + (((kk * 4 + quad) ^ (mrow & 7)) << 3));
    __builtin_amdgcn_s_setprio(1);
#pragma unroll
    for (int kk = 0; kk < 2; ++kk)
#pragma unroll
      for (int j = 0; j < 4; ++j) {
        bf16x8 vf = *(const bf16x8*)(Vt + (j * 16 + mrow) * 64
                                     + (((kk * 4 + quad) ^ (mrow & 7)) << 3));
        oacc[j] = __builtin_amdgcn_mfma_f32_16x16x32_bf16(pf[kk], vf, oacc[j], 0, 0, 0);
      }
    __builtin_amdgcn_s_setprio(0);

    // ---- pipelined staging: overwrite bufc with tile kt+2, counted wait ----
    if (kt < 15) {
      asm volatile("s_waitcnt lgkmcnt(0)" ::: "memory");
      __builtin_amdgcn_s_barrier();                // all waves done reading bufc
      if (kt < 14) {
        STAGE_T(kt + 2, cur);
        asm volatile("s_waitcnt vmcnt(3)" ::: "memory");   // tile kt+1 landed
      } else {
        asm volatile("s_waitcnt vmcnt(0)" ::: "memory");   // last tile landed
      }
      __builtin_amdgcn_s_barrier();                // buf[cur^1] ready for all
      asm volatile("" ::: "memory");
    }
  }
#undef STAGE_T

  // rowsum butterfly across 16 lanes (mrow)
#pragma unroll
  for (int d = 1; d < 16; d <<= 1) {
    f32x4 o;
#pragma unroll
    for (int r = 0; r < 4; ++r) o[r] = __shfl_xor(rsl[r], d, 64);
    rsl += o;
  }

  f32x4 inv;
#pragma unroll
  for (int r = 0; r < 4; ++r) inv[r] = 1.0f / (rsl[r] + 1e-6f);
#pragma unroll
  for (int j = 0; j < 4; ++j) {
    int col = hoff + j * 16 + mrow;
#pragma unroll
    for (int r = 0; r < 4; ++r) {
      int t = qt * 128 + w * 16 + quad * 4 + r;
      AO[(size_t)(t * 4 + b) * 1024 + col] = (__bf16)(oacc[j][r] * inv[r]);
    }
  }
}

extern "C" void kernel_launch(void* const* d_in, const int* in_sizes, int n_in,
                              void* d_out, int out_size, void* d_ws, size_t ws_size,
                              hipStream_t stream) {
  const float* query = (const float*)d_in[0];
  const float* key   = (const float*)d_in[1];
  const float* value = (const float*)d_in[2];
  const float* Wq    = (const float*)d_in[3];
  const float* Wk1   = (const float*)d_in[4];
  const float* Wk2   = (const float*)d_in[5];
  const float* Wv    = (const float*)d_in[6];
  const float* bin   = (const float*)d_in[7];
  const float* Wo    = (const float*)d_in[8];
  const float* bo    = (const float*)d_in[9];
  const float* pi    = (const float*)d_in[10];
  float* out = (float*)d_out;

  __bf16* qc  = (__bf16*)d_ws;          // 3*P4: qc|kc|vc
  __bf16* wq  = qc  + 3 * P4S;          // 5*P1: wq|wk1|wk2|wv|wo
  __bf16* wo  = wq  + 4 * P1S;
  __bf16* Qp  = wq  + 5 * P1S;          // 4*P4: Qp|K1p|K2p|Vp
  __bf16* K1p = Qp  + P4S;
  __bf16* K2p = K1p + P4S;
  __bf16* Vp  = K2p + P4S;
  __bf16* AO  = Vp  + P4S;
  float*  qn_g  = (float*)(AO + P4S);
  float*  kn1_g = qn_g  + 64 * 1024;
  float*  kn2_g = kn1_g + 64 * 1024;
  __bf16* Vt_g  = qc;                   // reuse: qc dead after proj_gemm4

  cvt_all<<<8704, 256, 0, stream>>>(query, key, value, Wq, Wk1, Wk2, Wv, Wo, qc);

  // 4 projections, 256x256 tiles: grid 16x4x4 = 256 blocks = 1 block/CU
  proj_gemm4<<<dim3(M_DIM / 256, E_DIM / 256, 4), 512, 0, stream>>>(qc, wq, bin, Qp);

  // merged norms + V transpose (one dispatch)
  norms_vt<<<768 + 1024, 256, 0, stream>>>(Qp, K1p, K2p, Vp,
                                           qn_g, kn1_g, kn2_g, Vt_g);

  // 128 q-rows/block, 8 waves: grid 64x8 = 512 blocks, 2 blocks/CU (64 KB LDS)
  mgk_attn_mfma<<<dim3(64, 8), 512, 0, stream>>>(
      Qp, K1p, K2p, Vt_g, qn_g, kn1_g, kn2_g, pi, AO);

  out_gemm<<<dim3(M_DIM / 128, E_DIM / 128), 256, 0, stream>>>(AO, wo, bo, out);
}